// Round 1
// baseline (2067.987 us; speedup 1.0000x reference)
//
#include <hip/hip_runtime.h>

#define EPS 1e-5f

// ---- workspace float offsets (params/stats region) ----
#define WS_SB1      0
#define WS_SB2      128
#define WS_STAT_C1  256
#define WS_COEF_C1  384
#define WS_STAT_QKV 512
#define WS_COEF_QKV 768
#define WS_STAT_SIM 1024
#define WS_COEF_SIM 1056
#define WS_STAT_OUT 1088
#define WS_COEF_OUT 1344
#define WS_STAT_C2  1600
#define WS_COEF_C2  1728
#define WS_STAT_END 1856

// ---- buffer regions (float offsets). Total ws use ~84 MB. ----
#define WS_R1  4096                   // 32 MiB region: out0 | t1t, later att, later conv2out
#define WS_R2  (WS_R1 + 8388608)      // 32 MiB region: qkv
#define WS_R3  (WS_R2 + 8388608)      // 16 MiB region: t2, later t3

__device__ __forceinline__ float wred(float v) {
    #pragma unroll
    for (int off = 32; off > 0; off >>= 1) v += __shfl_down(v, off, 64);
    return v;
}

// sb1 = cbn1_lin @ latent ; sb2 = cbn2_lin @ latent ; zero all stat accumulators
__global__ void k_prep0(const float* __restrict__ lin1, const float* __restrict__ lin2,
                        const float* __restrict__ latent, float* __restrict__ ws) {
    int t = threadIdx.x;
    for (int i = 256 + t; i < WS_STAT_END; i += 256) ws[i] = 0.f;
    const float* lin = (t < 128) ? lin1 : lin2;
    int row = t & 127;
    float s = 0.f;
    for (int l = 0; l < 256; ++l) s += lin[row * 256 + l] * latent[l];
    ws[(t < 128 ? WS_SB1 : WS_SB2) + row] = s;
}

// conv1: out0[b][o][hw] = sum_c w[o][c] * in[b][c][hw]
__global__ __launch_bounds__(256) void k_conv1(const float* __restrict__ in,
                                               const float* __restrict__ w,
                                               float* __restrict__ out) {
    __shared__ float ws_[4096];
    int t = threadIdx.x;
    for (int i = t; i < 4096; i += 256) ws_[i] = w[i];
    __syncthreads();
    int p  = blockIdx.x * 256 + t;          // 0..65535
    int b  = p >> 14, hw = p & 16383;
    const float* ip = in + b * 64 * 16384 + hw;
    float x[64];
    #pragma unroll
    for (int c = 0; c < 64; ++c) x[c] = ip[c * 16384];
    float* op = out + b * 64 * 16384 + hw;
    for (int o = 0; o < 64; ++o) {
        float acc = 0.f;
        #pragma unroll
        for (int c = 0; c < 64; ++c) acc += ws_[o * 64 + c] * x[c];
        op[o * 16384] = acc;
    }
}

// generic per-channel stats over [M][C][K]: stat[c] += sum, stat[C+c] += sumsq
__global__ void k_stats(const float* __restrict__ src, int C, int logK, int MK, int split,
                        float* __restrict__ stat) {
    int c = blockIdx.x % C;
    int chunk = blockIdx.x / C;
    int per = MK / split;
    int base = chunk * per;
    int Km1 = (1 << logK) - 1;
    float s = 0.f, ss = 0.f;
    for (int i = base + threadIdx.x; i < base + per; i += blockDim.x) {
        int m = i >> logK, k = i & Km1;
        float v = src[((m * C + c) << logK) + k];
        s += v; ss += v * v;
    }
    s = wred(s); ss = wred(ss);
    if ((threadIdx.x & 63) == 0) { atomicAdd(&stat[c], s); atomicAdd(&stat[C + c], ss); }
}

__global__ void k_prep_conv1(const float* __restrict__ g, const float* __restrict__ bta,
                             float* __restrict__ ws) {
    int c = threadIdx.x; if (c >= 64) return;
    float cnt = 65536.f;
    float mean = ws[WS_STAT_C1 + c] / cnt;
    float var  = ws[WS_STAT_C1 + 64 + c] / cnt - mean * mean;
    float tt = rsqrtf(var + EPS);
    float ab = g[c] * tt;
    float sc = ws[WS_SB1 + c], bi = ws[WS_SB1 + 64 + c];
    ws[WS_COEF_C1 + c] = sc * ab;
    ws[WS_COEF_C1 + 64 + c] = sc * (bta[c] - mean * ab) + bi;
}

// out0[b][c][h][w] -> t1t[b][w][c][h], applying affine + prelu
__global__ __launch_bounds__(256) void k_t1t(const float* __restrict__ src, float* __restrict__ dst,
                                             const float* __restrict__ ws,
                                             const float* __restrict__ prelu1) {
    __shared__ float tile[32][33];
    int bid = blockIdx.x;
    int wt = bid & 3, ht = (bid >> 2) & 3, c = (bid >> 4) & 63, b = bid >> 10;
    float A = ws[WS_COEF_C1 + c], Bb = ws[WS_COEF_C1 + 64 + c];
    float slope = *prelu1;
    int tx = threadIdx.x & 31, ty = threadIdx.x >> 5;
    const float* sp = src + ((b * 64 + c) * 128 + ht * 32) * 128 + wt * 32;
    for (int r = 0; r < 4; ++r) {
        float v = sp[(ty + r * 8) * 128 + tx];
        v = A * v + Bb;
        v = v >= 0.f ? v : slope * v;
        tile[ty + r * 8][tx] = v;   // tile[h][w]
    }
    __syncthreads();
    float* dp = dst + b * 1048576 + (wt * 32) * 8192 + c * 128 + ht * 32;
    for (int r = 0; r < 4; ++r)
        dp[(ty + r * 8) * 8192 + tx] = tile[tx][ty + r * 8];
}

// qkv[n][o][a] = sum_c w[o][c] * x(b, r, c, a) with addr = b*SB + r*SR + c*SC + a
__global__ __launch_bounds__(256) void k_qkv(const float* __restrict__ x, const float* __restrict__ w,
                                             float* __restrict__ out, int SB, int SR, int SC) {
    __shared__ float ws_[8192];
    __shared__ float xs[64][128];
    int t = threadIdx.x;
    for (int i = t; i < 8192; i += 256) ws_[i] = w[i];
    int n = blockIdx.x;
    int b = n >> 7, r = n & 127;
    const float* xp = x + b * SB + r * SR;
    for (int i = t; i < 8192; i += 256) {
        int c = i >> 7, a = i & 127;
        xs[c][a] = xp[c * SC + a];
    }
    __syncthreads();
    int a = t & 127, oh = t >> 7;
    float xc[64];
    #pragma unroll
    for (int c = 0; c < 64; ++c) xc[c] = xs[c][a];
    float* op = out + n * 16384 + oh * 8192 + a;
    for (int o = 0; o < 64; ++o) {
        const float* wr = &ws_[(oh * 64 + o) * 64];
        float acc = 0.f;
        #pragma unroll
        for (int c = 0; c < 64; ++c) acc += wr[c] * xc[c];
        op[o * 128] = acc;
    }
}

__global__ void k_prep_qkv(const float* __restrict__ g, const float* __restrict__ bta,
                           float* __restrict__ ws) {
    int c = threadIdx.x; if (c >= 128) return;
    float cnt = 65536.f;
    float mean = ws[WS_STAT_QKV + c] / cnt;
    float var  = ws[WS_STAT_QKV + 128 + c] / cnt - mean * mean;
    float tt = rsqrtf(var + EPS);
    float A = g[c] * tt;
    ws[WS_COEF_QKV + c] = A;
    ws[WS_COEF_QKV + 128 + c] = bta[c] - mean * A;
}

// passA: per (n,g): build q_emb/k_emb in LDS, compute qk tiles; accumulate sim stats only.
__global__ __launch_bounds__(256) void k_passA(const float* __restrict__ qkv,
                                               const float* __restrict__ remb,
                                               float* __restrict__ ws) {
    __shared__ float qe[128][128];
    __shared__ float ke[128][128];
    __shared__ float re[16][255];
    __shared__ float qs[16][128];
    int t = threadIdx.x;
    int n = blockIdx.x >> 2, g = blockIdx.x & 3;
    for (int i = t; i < 16 * 255; i += 256) { int c = i / 255, d = i % 255; re[c][d] = remb[c * 255 + d]; }
    for (int i = t; i < 2048; i += 256) {
        int c = i >> 7, a = i & 127;
        int o = g * 32 + c;
        qs[c][a] = ws[WS_COEF_QKV + o] * qkv[n * 16384 + o * 128 + a] + ws[WS_COEF_QKV + 128 + o];
    }
    __syncthreads();
    float s1 = 0.f, s2 = 0.f, s3 = 0.f, s4 = 0.f;
    for (int i = t; i < 16384; i += 256) {
        int tt = i >> 7, j = i & 127;
        int d = 127 + tt - j;
        float aq = 0.f, ak = 0.f;
        #pragma unroll
        for (int c = 0; c < 8; ++c) {
            aq += qs[c][tt] * re[c][d];
            ak += qs[8 + c][tt] * re[8 + c][d];
        }
        qe[tt][j] = aq; ke[tt][j] = ak;
        s1 += aq; s2 += aq * aq; s3 += ak; s4 += ak * ak;
    }
    s1 = wred(s1); s2 = wred(s2); s3 = wred(s3); s4 = wred(s4);
    if ((t & 63) == 0) {
        atomicAdd(&ws[WS_STAT_SIM + 4 + g], s1);  atomicAdd(&ws[WS_STAT_SIM + 16 + g], s2);
        atomicAdd(&ws[WS_STAT_SIM + 8 + g], s3);  atomicAdd(&ws[WS_STAT_SIM + 20 + g], s4);
    }
    __syncthreads();
    int i0 = (t & 15) * 8, j0 = (t >> 4) * 8;
    float acc[8][8];
    #pragma unroll
    for (int u = 0; u < 8; ++u)
        #pragma unroll
        for (int v = 0; v < 8; ++v) acc[u][v] = 0.f;
    for (int tt = 0; tt < 128; ++tt) {
        const float4* qp = reinterpret_cast<const float4*>(&qe[tt][i0]);
        const float4* kp = reinterpret_cast<const float4*>(&ke[tt][j0]);
        float4 qa = qp[0], qb = qp[1], ka = kp[0], kb = kp[1];
        float qv[8] = {qa.x, qa.y, qa.z, qa.w, qb.x, qb.y, qb.z, qb.w};
        float kv[8] = {ka.x, ka.y, ka.z, ka.w, kb.x, kb.y, kb.z, kb.w};
        #pragma unroll
        for (int u = 0; u < 8; ++u)
            #pragma unroll
            for (int v = 0; v < 8; ++v) acc[u][v] += qv[u] * kv[v];
    }
    float s = 0.f, ssq = 0.f;
    #pragma unroll
    for (int u = 0; u < 8; ++u)
        #pragma unroll
        for (int v = 0; v < 8; ++v) { float x = acc[u][v]; s += x; ssq += x * x; }
    s = wred(s); ssq = wred(ssq);
    if ((t & 63) == 0) { atomicAdd(&ws[WS_STAT_SIM + g], s); atomicAdd(&ws[WS_STAT_SIM + 12 + g], ssq); }
}

// stat_sim layout: sums[12] @0, sumsq[12] @12  (ch: qk=g, q_emb=4+g, k_emb=8+g)
__global__ void k_prep_sim(const float* __restrict__ g, const float* __restrict__ bta,
                           float* __restrict__ ws) {
    int i = threadIdx.x; if (i >= 4) return;
    float cnt = 8388608.f;
    float aa[3], bb[3];
    for (int k = 0; k < 3; ++k) {
        int ch = k * 4 + i;
        float mean = ws[WS_STAT_SIM + ch] / cnt;
        float var  = ws[WS_STAT_SIM + 12 + ch] / cnt - mean * mean;
        float tt = rsqrtf(var + EPS);
        float A = g[ch] * tt;
        aa[k] = A; bb[k] = bta[ch] - mean * A;
    }
    ws[WS_COEF_SIM + i]      = aa[0];
    ws[WS_COEF_SIM + 4 + i]  = aa[1];
    ws[WS_COEF_SIM + 8 + i]  = aa[2];
    ws[WS_COEF_SIM + 12 + i] = bb[0] + bb[1] + bb[2];
}

// passB: recompute, BN-combine, softmax, am/ame, write att[n][128ch][a]
__global__ __launch_bounds__(256) void k_passB(const float* __restrict__ qkv,
                                               const float* __restrict__ remb,
                                               const float* __restrict__ ws,
                                               float* __restrict__ att) {
    __shared__ float qe[128][128];   // reused as p_lds[j][i]
    __shared__ float ke[128][128];
    __shared__ float re[16][255];    // emb rows 0-15; scratch; then ve rows 16-31
    __shared__ float qs[16][128];    // q/k rows during fill; v rows during am
    int t = threadIdx.x;
    int n = blockIdx.x >> 2, g = blockIdx.x & 3;
    for (int i = t; i < 16 * 255; i += 256) { int c = i / 255, d = i % 255; re[c][d] = remb[c * 255 + d]; }
    // stage q(0-7), k(8-15) interleaved into qs: q in rows 0-7 and k rows 8-15
    for (int i = t; i < 2048; i += 256) {
        int c = i >> 7, a = i & 127;
        int o = g * 32 + c;
        qs[c][a] = ws[WS_COEF_QKV + o] * qkv[n * 16384 + o * 128 + a] + ws[WS_COEF_QKV + 128 + o];
    }
    __syncthreads();
    for (int i = t; i < 16384; i += 256) {
        int tt = i >> 7, j = i & 127;
        int d = 127 + tt - j;
        float aq = 0.f, ak = 0.f;
        #pragma unroll
        for (int c = 0; c < 8; ++c) {
            aq += qs[c][tt] * re[c][d];
            ak += qs[8 + c][tt] * re[8 + c][d];
        }
        qe[tt][j] = aq; ke[tt][j] = ak;
    }
    __syncthreads();
    float Aqk = ws[WS_COEF_SIM + g],     Aqe = ws[WS_COEF_SIM + 4 + g];
    float Ake = ws[WS_COEF_SIM + 8 + g], Cst = ws[WS_COEF_SIM + 12 + g];
    int i0 = (t & 15) * 8, j0 = (t >> 4) * 8, jt = t >> 4;
    float acc[8][8];
    #pragma unroll
    for (int u = 0; u < 8; ++u)
        #pragma unroll
        for (int v = 0; v < 8; ++v) acc[u][v] = 0.f;
    for (int tt = 0; tt < 128; ++tt) {
        const float4* qp = reinterpret_cast<const float4*>(&qe[tt][i0]);
        const float4* kp = reinterpret_cast<const float4*>(&ke[tt][j0]);
        float4 qa = qp[0], qb = qp[1], ka = kp[0], kb = kp[1];
        float qv[8] = {qa.x, qa.y, qa.z, qa.w, qb.x, qb.y, qb.z, qb.w};
        float kv[8] = {ka.x, ka.y, ka.z, ka.w, kb.x, kb.y, kb.z, kb.w};
        #pragma unroll
        for (int u = 0; u < 8; ++u)
            #pragma unroll
            for (int v = 0; v < 8; ++v) acc[u][v] += qv[u] * kv[v];
    }
    // sim = Aqk*qk + Aqe*q_emb[i][j] + Ake*k_emb[i][j] + Cst
    #pragma unroll
    for (int u = 0; u < 8; ++u) {
        const float4* qp = reinterpret_cast<const float4*>(&qe[i0 + u][j0]);
        const float4* kp = reinterpret_cast<const float4*>(&ke[i0 + u][j0]);
        float4 qa = qp[0], qb = qp[1], ka = kp[0], kb = kp[1];
        float qv[8] = {qa.x, qa.y, qa.z, qa.w, qb.x, qb.y, qb.z, qb.w};
        float kv[8] = {ka.x, ka.y, ka.z, ka.w, kb.x, kb.y, kb.z, kb.w};
        #pragma unroll
        for (int v = 0; v < 8; ++v)
            acc[u][v] = Aqk * acc[u][v] + Aqe * qv[v] + Ake * kv[v] + Cst;
    }
    // softmax over j (rows = i). scratch aliased into re region.
    float* sc = &re[0][0];          // 128*16
    float* rowv = sc + 2048;        // 128
    #pragma unroll
    for (int u = 0; u < 8; ++u) {
        float m = acc[u][0];
        #pragma unroll
        for (int v = 1; v < 8; ++v) m = fmaxf(m, acc[u][v]);
        sc[(i0 + u) * 16 + jt] = m;
    }
    __syncthreads();
    if (t < 128) {
        float m = sc[t * 16];
        for (int k = 1; k < 16; ++k) m = fmaxf(m, sc[t * 16 + k]);
        rowv[t] = m;
    }
    __syncthreads();
    #pragma unroll
    for (int u = 0; u < 8; ++u) {
        float m = rowv[i0 + u], s = 0.f;
        #pragma unroll
        for (int v = 0; v < 8; ++v) { acc[u][v] = __expf(acc[u][v] - m); s += acc[u][v]; }
        sc[(i0 + u) * 16 + jt] = s;
    }
    __syncthreads();
    if (t < 128) {
        float s = 0.f;
        for (int k = 0; k < 16; ++k) s += sc[t * 16 + k];
        rowv[t] = 1.f / s;
    }
    __syncthreads();
    // p transposed into qe region: pl[j][i]
    float (*pl)[128] = qe;
    #pragma unroll
    for (int u = 0; u < 8; ++u) {
        float inv = rowv[i0 + u];
        #pragma unroll
        for (int v = 0; v < 8; ++v) pl[j0 + v][i0 + u] = acc[u][v] * inv;
    }
    __syncthreads();
    // reload re with ve rows (16..31), qs with v rows (g*32+16..)
    for (int i = t; i < 16 * 255; i += 256) { int c = i / 255, d = i % 255; re[c][d] = remb[(16 + c) * 255 + d]; }
    for (int i = t; i < 2048; i += 256) {
        int c = i >> 7, a = i & 127;
        int o = g * 32 + 16 + c;
        qs[c][a] = ws[WS_COEF_QKV + o] * qkv[n * 16384 + o * 128 + a] + ws[WS_COEF_QKV + 128 + o];
    }
    __syncthreads();
    // am[c][i] = sum_j p[i][j]*v[c][j]; ame[c][i] = sum_j p[i][j]*re[c][127+i-j]
    int ii = t & 127, cbase = (t >> 7) * 8;
    float am[8], ame[8];
    #pragma unroll
    for (int c = 0; c < 8; ++c) { am[c] = 0.f; ame[c] = 0.f; }
    for (int j = 0; j < 128; ++j) {
        float p = pl[j][ii];
        int d = 127 + ii - j;
        #pragma unroll
        for (int c = 0; c < 8; ++c) {
            am[c]  += p * qs[cbase + c][j];
            ame[c] += p * re[cbase + c][d];
        }
    }
    float* ap = att + n * 16384 + (g * 32) * 128 + ii;
    #pragma unroll
    for (int c = 0; c < 8; ++c) {
        ap[(2 * (cbase + c)) * 128]     = am[c];
        ap[(2 * (cbase + c) + 1) * 128] = ame[c];
    }
}

__global__ void k_prep_out(const float* __restrict__ g, const float* __restrict__ bta,
                           float* __restrict__ ws) {
    int c = threadIdx.x; if (c >= 128) return;
    float cnt = 65536.f;
    float mean = ws[WS_STAT_OUT + c] / cnt;
    float var  = ws[WS_STAT_OUT + 128 + c] / cnt - mean * mean;
    float tt = rsqrtf(var + EPS);
    float A = g[c] * tt;
    ws[WS_COEF_OUT + c] = A;
    ws[WS_COEF_OUT + 128 + c] = bta[c] - mean * A;
}

// axial0 finish: att[n=b*128+w][ch][h] -> t2[b][c][h][w], affine + pair-sum, tiled transpose
__global__ __launch_bounds__(256) void k_finish0(const float* __restrict__ att,
                                                 const float* __restrict__ ws,
                                                 float* __restrict__ t2) {
    __shared__ float tile[16][32][33];
    int bid = blockIdx.x;
    int wt = bid & 3, ht = (bid >> 2) & 3, cg = (bid >> 4) & 7, b = bid >> 7;
    int t = threadIdx.x;
    for (int i = t; i < 16384; i += 256) {
        int h = i & 31, w = (i >> 5) & 31, cl = i >> 10;
        int c_out = cg * 8 + (cl >> 1), s = cl & 1;
        int chg = (c_out >> 4) * 32 + (c_out & 15) * 2 + s;
        float v = att[((b * 128 + wt * 32 + w) * 128 + chg) * 128 + ht * 32 + h];
        tile[cl][w][h] = ws[WS_COEF_OUT + chg] * v + ws[WS_COEF_OUT + 128 + chg];
    }
    __syncthreads();
    for (int i = t; i < 8192; i += 256) {
        int w = i & 31, h = (i >> 5) & 31, cl = i >> 10;
        float v = tile[2 * cl][w][h] + tile[2 * cl + 1][w][h];
        t2[((b * 64 + cg * 8 + cl) * 128 + ht * 32 + h) * 128 + wt * 32 + w] = v;
    }
}

__global__ void k_zero2(float* __restrict__ ws) {
    int t = threadIdx.x;
    if (t < 256) ws[WS_STAT_QKV + t] = 0.f;
    if (t < 24)  ws[WS_STAT_SIM + t] = 0.f;
    if (t < 256) ws[WS_STAT_OUT + t] = 0.f;
}

// axial1 finish: att[n=b*128+h][ch][w] -> t3[b][c][h][w] (no transpose)
__global__ __launch_bounds__(256) void k_finish1(const float* __restrict__ att,
                                                 const float* __restrict__ ws,
                                                 float* __restrict__ t3) {
    int idx = blockIdx.x * 256 + threadIdx.x;   // < 4194304
    int w = idx & 127, h = (idx >> 7) & 127, c = (idx >> 14) & 63, b = idx >> 20;
    int chg = (c >> 4) * 32 + (c & 15) * 2;
    int base = ((b * 128 + h) * 128 + chg) * 128 + w;
    float v0 = att[base], v1 = att[base + 128];
    t3[idx] = ws[WS_COEF_OUT + chg] * v0 + ws[WS_COEF_OUT + 128 + chg]
            + ws[WS_COEF_OUT + chg + 1] * v1 + ws[WS_COEF_OUT + 129 + chg];
}

// avgpool2(t3) then conv: out[b][o][y*64+x]
__global__ __launch_bounds__(256) void k_conv2(const float* __restrict__ t3,
                                               const float* __restrict__ w,
                                               float* __restrict__ out) {
    __shared__ float ws_[4096];
    int t = threadIdx.x;
    for (int i = t; i < 4096; i += 256) ws_[i] = w[i];
    __syncthreads();
    int p = blockIdx.x * 256 + t;       // < 16384
    int b = p >> 12, yx = p & 4095, y = yx >> 6, x = yx & 63;
    const float* tp = t3 + b * 1048576 + (2 * y) * 128 + 2 * x;
    float xc[64];
    #pragma unroll
    for (int c = 0; c < 64; ++c) {
        const float* q = tp + c * 16384;
        xc[c] = 0.25f * (q[0] + q[1] + q[128] + q[129]);
    }
    float* op = out + b * 262144 + yx;
    for (int o = 0; o < 64; ++o) {
        float acc = 0.f;
        #pragma unroll
        for (int c = 0; c < 64; ++c) acc += ws_[o * 64 + c] * xc[c];
        op[o * 4096] = acc;
    }
}

__global__ void k_prep_cbn2(const float* __restrict__ g, const float* __restrict__ bta,
                            float* __restrict__ ws) {
    int c = threadIdx.x; if (c >= 64) return;
    float cnt = 16384.f;
    float mean = ws[WS_STAT_C2 + c] / cnt;
    float var  = ws[WS_STAT_C2 + 64 + c] / cnt - mean * mean;
    float tt = rsqrtf(var + EPS);
    float ab = g[c] * tt;
    float sc = ws[WS_SB2 + c], bi = ws[WS_SB2 + 64 + c];
    ws[WS_COEF_C2 + c] = sc * ab;
    ws[WS_COEF_C2 + 64 + c] = sc * (bta[c] - mean * ab) + bi;
}

__global__ __launch_bounds__(256) void k_final(const float* __restrict__ c2out,
                                               const float* __restrict__ input,
                                               const float* __restrict__ ws,
                                               const float* __restrict__ prelu2,
                                               float* __restrict__ out) {
    int idx = blockIdx.x * 256 + threadIdx.x;   // < 1048576
    int x = idx & 63, y = (idx >> 6) & 63, o = (idx >> 12) & 63, b = idx >> 18;
    float v = ws[WS_COEF_C2 + o] * c2out[idx] + ws[WS_COEF_C2 + 64 + o];
    const float* ip = input + ((b * 64 + o) * 128 + 2 * y) * 128 + 2 * x;
    v += 0.25f * (ip[0] + ip[1] + ip[128] + ip[129]);
    float s = *prelu2;
    out[idx] = v >= 0.f ? v : s * v;
}

extern "C" void kernel_launch(void* const* d_in, const int* in_sizes, int n_in,
                              void* d_out, int out_size, void* d_ws, size_t ws_size,
                              hipStream_t stream) {
    const float* input    = (const float*)d_in[0];
    const float* latent   = (const float*)d_in[1];
    const float* w_in     = (const float*)d_in[2];
    const float* cbn1_g   = (const float*)d_in[3];
    const float* cbn1_b   = (const float*)d_in[4];
    const float* cbn1_lin = (const float*)d_in[5];
    const float* prelu1   = (const float*)d_in[6];
    const float* ax_qkv_w[2] = {(const float*)d_in[7],  (const float*)d_in[15]};
    const float* ax_qkv_g[2] = {(const float*)d_in[8],  (const float*)d_in[16]};
    const float* ax_qkv_b[2] = {(const float*)d_in[9],  (const float*)d_in[17]};
    const float* ax_sim_g[2] = {(const float*)d_in[10], (const float*)d_in[18]};
    const float* ax_sim_b[2] = {(const float*)d_in[11], (const float*)d_in[19]};
    const float* ax_rel[2]   = {(const float*)d_in[12], (const float*)d_in[20]};
    const float* ax_out_g[2] = {(const float*)d_in[13], (const float*)d_in[21]};
    const float* ax_out_b[2] = {(const float*)d_in[14], (const float*)d_in[22]};
    const float* w_out    = (const float*)d_in[23];
    const float* cbn2_g   = (const float*)d_in[24];
    const float* cbn2_b   = (const float*)d_in[25];
    const float* cbn2_lin = (const float*)d_in[26];
    const float* prelu2   = (const float*)d_in[27];

    float* ws   = (float*)d_ws;
    float* out0 = ws + WS_R1;            // 16 MiB (first half of R1)
    float* t1t  = ws + WS_R1 + 4194304;  // 16 MiB (second half of R1)
    float* att  = ws + WS_R1;            // 32 MiB (whole R1, after t1t dead)
    float* c2o  = ws + WS_R1;            // 1 MiB  (after att dead)
    float* qkv  = ws + WS_R2;            // 32 MiB
    float* t23  = ws + WS_R3;            // 16 MiB (t2 then t3)
    float* dst  = (float*)d_out;

    k_prep0<<<1, 256, 0, stream>>>(cbn1_lin, cbn2_lin, latent, ws);
    k_conv1<<<256, 256, 0, stream>>>(input, w_in, out0);
    k_stats<<<1024, 256, 0, stream>>>(out0, 64, 14, 65536, 16, ws + WS_STAT_C1);
    k_prep_conv1<<<1, 64, 0, stream>>>(cbn1_g, cbn1_b, ws);
    k_t1t<<<4096, 256, 0, stream>>>(out0, t1t, ws, prelu1);

    // axial 0 (n = b*128 + w, a = h), x from t1t[b][w][c][h]
    k_qkv<<<512, 256, 0, stream>>>(t1t, ax_qkv_w[0], qkv, 1048576, 8192, 128);
    k_stats<<<1024, 256, 0, stream>>>(qkv, 128, 7, 65536, 8, ws + WS_STAT_QKV);
    k_prep_qkv<<<1, 128, 0, stream>>>(ax_qkv_g[0], ax_qkv_b[0], ws);
    k_passA<<<2048, 256, 0, stream>>>(qkv, ax_rel[0], ws);
    k_prep_sim<<<1, 64, 0, stream>>>(ax_sim_g[0], ax_sim_b[0], ws);
    k_passB<<<2048, 256, 0, stream>>>(qkv, ax_rel[0], ws, att);
    k_stats<<<1024, 256, 0, stream>>>(att, 128, 7, 65536, 8, ws + WS_STAT_OUT);
    k_prep_out<<<1, 128, 0, stream>>>(ax_out_g[0], ax_out_b[0], ws);
    k_finish0<<<512, 256, 0, stream>>>(att, ws, t23);
    k_zero2<<<1, 256, 0, stream>>>(ws);

    // axial 1 (n = b*128 + h, a = w), x from t2[b][c][h][w]
    k_qkv<<<512, 256, 0, stream>>>(t23, ax_qkv_w[1], qkv, 1048576, 128, 16384);
    k_stats<<<1024, 256, 0, stream>>>(qkv, 128, 7, 65536, 8, ws + WS_STAT_QKV);
    k_prep_qkv<<<1, 128, 0, stream>>>(ax_qkv_g[1], ax_qkv_b[1], ws);
    k_passA<<<2048, 256, 0, stream>>>(qkv, ax_rel[1], ws);
    k_prep_sim<<<1, 64, 0, stream>>>(ax_sim_g[1], ax_sim_b[1], ws);
    k_passB<<<2048, 256, 0, stream>>>(qkv, ax_rel[1], ws, att);
    k_stats<<<1024, 256, 0, stream>>>(att, 128, 7, 65536, 8, ws + WS_STAT_OUT);
    k_prep_out<<<1, 128, 0, stream>>>(ax_out_g[1], ax_out_b[1], ws);
    k_finish1<<<16384, 256, 0, stream>>>(att, ws, t23);

    // tail: pool+conv2, cbn2, residual, prelu
    k_conv2<<<64, 256, 0, stream>>>(t23, w_out, c2o);
    k_stats<<<256, 256, 0, stream>>>(c2o, 64, 12, 16384, 4, ws + WS_STAT_C2);
    k_prep_cbn2<<<1, 64, 0, stream>>>(cbn2_g, cbn2_b, ws);
    k_final<<<4096, 256, 0, stream>>>(c2o, input, ws, prelu2, dst);
}

// Round 2
// 817.008 us; speedup vs baseline: 2.5312x; 2.5312x over previous
//
#include <hip/hip_runtime.h>

#define EPS 1e-5f

typedef __attribute__((ext_vector_type(4))) _Float16 h4;
typedef __attribute__((ext_vector_type(8))) _Float16 h8;
typedef __attribute__((ext_vector_type(4))) float f4;

// ---- workspace float offsets (params/stats region) ----
#define WS_SB1      0
#define WS_SB2      128
#define WS_STAT_C1  256
#define WS_COEF_C1  384
#define WS_STAT_QKV 512
#define WS_COEF_QKV 768
#define WS_STAT_SIM 1024
#define WS_COEF_SIM 1056
#define WS_STAT_OUT 1088
#define WS_COEF_OUT 1344
#define WS_STAT_C2  1600
#define WS_COEF_C2  1728
#define WS_STAT_END 1856

// ---- buffer regions (float offsets) ----
#define WS_R1  4096
#define WS_R2  (WS_R1 + 8388608)
#define WS_R3  (WS_R2 + 8388608)

// ---- pass-kernel LDS byte offsets (total 81920 = 80 KiB -> 2 blocks/CU) ----
#define L_QEA 0        // [128 rows b][128 a] fp16, 256B rows, swz ^((b&7)<<4); reused as P[i][j]
#define L_KEB 32768    // same layout for K_emb
#define L_RET 65536    // [256 d][16 c] fp16, 32B rows, swz ^((d&4)<<2); build re(0-15) then ve(16-31)
#define L_AQ  73728    // [128 a][16 c] fp16, 32B rows, swz ^((a&4)<<2); q in c0-7; reused as V[16][128]
#define L_AK  77824    // k in c8-15; reused post-build as f32 red[] scratch (passA)
#define L_V   73728

__device__ __forceinline__ float wred(float v) {
    #pragma unroll
    for (int off = 32; off > 0; off >>= 1) v += __shfl_down(v, off, 64);
    return v;
}

// sb1 = cbn1_lin @ latent ; sb2 = cbn2_lin @ latent ; zero all stat accumulators
__global__ void k_prep0(const float* __restrict__ lin1, const float* __restrict__ lin2,
                        const float* __restrict__ latent, float* __restrict__ ws) {
    int t = threadIdx.x;
    for (int i = 256 + t; i < WS_STAT_END; i += 256) ws[i] = 0.f;
    const float* lin = (t < 128) ? lin1 : lin2;
    int row = t & 127;
    float s = 0.f;
    for (int l = 0; l < 256; ++l) s += lin[row * 256 + l] * latent[l];
    ws[(t < 128 ? WS_SB1 : WS_SB2) + row] = s;
}

// conv1: out0[b][o][hw] = sum_c w[o][c] * in[b][c][hw]
__global__ __launch_bounds__(256) void k_conv1(const float* __restrict__ in,
                                               const float* __restrict__ w,
                                               float* __restrict__ out) {
    __shared__ float ws_[4096];
    int t = threadIdx.x;
    for (int i = t; i < 4096; i += 256) ws_[i] = w[i];
    __syncthreads();
    int p  = blockIdx.x * 256 + t;
    int b  = p >> 14, hw = p & 16383;
    const float* ip = in + b * 64 * 16384 + hw;
    float x[64];
    #pragma unroll
    for (int c = 0; c < 64; ++c) x[c] = ip[c * 16384];
    float* op = out + b * 64 * 16384 + hw;
    for (int o = 0; o < 64; ++o) {
        float acc = 0.f;
        #pragma unroll
        for (int c = 0; c < 64; ++c) acc += ws_[o * 64 + c] * x[c];
        op[o * 16384] = acc;
    }
}

// generic per-channel stats over [M][C][K]
__global__ void k_stats(const float* __restrict__ src, int C, int logK, int MK, int split,
                        float* __restrict__ stat) {
    int c = blockIdx.x % C;
    int chunk = blockIdx.x / C;
    int per = MK / split;
    int base = chunk * per;
    int Km1 = (1 << logK) - 1;
    float s = 0.f, ss = 0.f;
    for (int i = base + threadIdx.x; i < base + per; i += blockDim.x) {
        int m = i >> logK, k = i & Km1;
        float v = src[((m * C + c) << logK) + k];
        s += v; ss += v * v;
    }
    s = wred(s); ss = wred(ss);
    if ((threadIdx.x & 63) == 0) { atomicAdd(&stat[c], s); atomicAdd(&stat[C + c], ss); }
}

__global__ void k_prep_conv1(const float* __restrict__ g, const float* __restrict__ bta,
                             float* __restrict__ ws) {
    int c = threadIdx.x; if (c >= 64) return;
    float cnt = 65536.f;
    float mean = ws[WS_STAT_C1 + c] / cnt;
    float var  = ws[WS_STAT_C1 + 64 + c] / cnt - mean * mean;
    float tt = rsqrtf(var + EPS);
    float ab = g[c] * tt;
    float sc = ws[WS_SB1 + c], bi = ws[WS_SB1 + 64 + c];
    ws[WS_COEF_C1 + c] = sc * ab;
    ws[WS_COEF_C1 + 64 + c] = sc * (bta[c] - mean * ab) + bi;
}

// out0[b][c][h][w] -> t1t[b][w][c][h], affine + prelu
__global__ __launch_bounds__(256) void k_t1t(const float* __restrict__ src, float* __restrict__ dst,
                                             const float* __restrict__ ws,
                                             const float* __restrict__ prelu1) {
    __shared__ float tile[32][33];
    int bid = blockIdx.x;
    int wt = bid & 3, ht = (bid >> 2) & 3, c = (bid >> 4) & 63, b = bid >> 10;
    float A = ws[WS_COEF_C1 + c], Bb = ws[WS_COEF_C1 + 64 + c];
    float slope = *prelu1;
    int tx = threadIdx.x & 31, ty = threadIdx.x >> 5;
    const float* sp = src + ((b * 64 + c) * 128 + ht * 32) * 128 + wt * 32;
    for (int r = 0; r < 4; ++r) {
        float v = sp[(ty + r * 8) * 128 + tx];
        v = A * v + Bb;
        v = v >= 0.f ? v : slope * v;
        tile[ty + r * 8][tx] = v;
    }
    __syncthreads();
    float* dp = dst + b * 1048576 + (wt * 32) * 8192 + c * 128 + ht * 32;
    for (int r = 0; r < 4; ++r)
        dp[(ty + r * 8) * 8192 + tx] = tile[tx][ty + r * 8];
}

// qkv[n][o][a] = sum_c w[o][c] * x(b, r, c, a)
__global__ __launch_bounds__(256) void k_qkv(const float* __restrict__ x, const float* __restrict__ w,
                                             float* __restrict__ out, int SB, int SR, int SC) {
    __shared__ float ws_[8192];
    __shared__ float xs[64][128];
    int t = threadIdx.x;
    for (int i = t; i < 8192; i += 256) ws_[i] = w[i];
    int n = blockIdx.x;
    int b = n >> 7, r = n & 127;
    const float* xp = x + b * SB + r * SR;
    for (int i = t; i < 8192; i += 256) {
        int c = i >> 7, a = i & 127;
        xs[c][a] = xp[c * SC + a];
    }
    __syncthreads();
    int a = t & 127, oh = t >> 7;
    float xc[64];
    #pragma unroll
    for (int c = 0; c < 64; ++c) xc[c] = xs[c][a];
    float* op = out + n * 16384 + oh * 8192 + a;
    for (int o = 0; o < 64; ++o) {
        const float* wr = &ws_[(oh * 64 + o) * 64];
        float acc = 0.f;
        #pragma unroll
        for (int c = 0; c < 64; ++c) acc += wr[c] * xc[c];
        op[o * 128] = acc;
    }
}

__global__ void k_prep_qkv(const float* __restrict__ g, const float* __restrict__ bta,
                           float* __restrict__ ws) {
    int c = threadIdx.x; if (c >= 128) return;
    float cnt = 65536.f;
    float mean = ws[WS_STAT_QKV + c] / cnt;
    float var  = ws[WS_STAT_QKV + 128 + c] / cnt - mean * mean;
    float tt = rsqrtf(var + EPS);
    float A = g[c] * tt;
    ws[WS_COEF_QKV + c] = A;
    ws[WS_COEF_QKV + 128 + c] = bta[c] - mean * A;
}

// ---- shared device helpers for passes ----
__device__ __forceinline__ void stage_aqk(unsigned char* L, const float* qkv, const float* ws,
                                          int n, int g, int t) {
    const float* qp = qkv + n * 16384 + g * 32 * 128;
    #pragma unroll
    for (int k = 0; k < 8; ++k) {
        int i = t + k * 256;
        int a = i & 127, cc = i >> 7;
        float v = ws[WS_COEF_QKV + g * 32 + cc] * qp[cc * 128 + a] + ws[WS_COEF_QKV + 128 + g * 32 + cc];
        _Float16 h = (_Float16)v;
        int off = a * 32 + ((cc * 2) ^ ((a & 4) << 2));
        *(_Float16*)(L + L_AQ + off) = (cc < 8) ? h : (_Float16)0.f;
        *(_Float16*)(L + L_AK + off) = (cc < 8) ? (_Float16)0.f : h;
    }
}

__device__ __forceinline__ void stage_ret(unsigned char* L, const float* remb, int crow0, int t) {
    #pragma unroll
    for (int k = 0; k < 16; ++k) {
        int i = t + k * 256;
        int d = i & 255, c = i >> 8;
        float v = (d < 255) ? remb[(crow0 + c) * 255 + d] : 0.f;
        *(_Float16*)(L + L_RET + d * 32 + ((c * 2) ^ ((d & 4) << 2))) = (_Float16)v;
    }
}

// build q_emb/k_emb via MFMA over diagonals and scatter fp16 into qeA/keB.
// returns emb sums in s[4] = {qe_s, qe_ss, ke_s, ke_ss} (per-lane partials)
__device__ __forceinline__ void build_emb(unsigned char* L, int w, int l15, int g4, float* s) {
    #pragma unroll
    for (int ah = 0; ah < 2; ++ah) {
        int at = w * 2 + ah;
        int arow = at * 16 + l15;
        int aoff = arow * 32 + ((g4 * 8) ^ ((arow & 4) << 2));
        h4 aq = *(const h4*)(L + L_AQ + aoff);
        h4 ak = *(const h4*)(L + L_AK + aoff);
        int abase = at * 16 + g4 * 4;
        for (int dt = 0; dt < 16; ++dt) {
            int drow = dt * 16 + l15;
            h4 bf = *(const h4*)(L + L_RET + drow * 32 + ((g4 * 8) ^ ((drow & 4) << 2)));
            f4 z = {0.f, 0.f, 0.f, 0.f};
            f4 dq = __builtin_amdgcn_mfma_f32_16x16x16f16(aq, bf, z, 0, 0, 0);
            f4 dk = __builtin_amdgcn_mfma_f32_16x16x16f16(ak, bf, z, 0, 0, 0);
            #pragma unroll
            for (int r = 0; r < 4; ++r) {
                int a = abase + r;
                int b = 127 + a - drow;
                if (b >= 0 && b < 128) {
                    int off = b * 256 + ((a * 2) ^ ((b & 7) << 4));
                    *(_Float16*)(L + L_QEA + off) = (_Float16)dq[r];
                    *(_Float16*)(L + L_KEB + off) = (_Float16)dk[r];
                    s[0] += dq[r]; s[1] += dq[r] * dq[r];
                    s[2] += dk[r]; s[3] += dk[r] * dk[r];
                }
            }
        }
    }
}

__device__ __forceinline__ void qk_mfma(unsigned char* L, int i0, int l15, int g4, f4 acc[2][8]) {
    h8 af[2][4];
    #pragma unroll
    for (int ti = 0; ti < 2; ++ti)
        #pragma unroll
        for (int ks = 0; ks < 4; ++ks) {
            int row = i0 + ti * 16 + l15;
            af[ti][ks] = *(const h8*)(L + L_QEA + row * 256 + ((ks * 64 + g4 * 16) ^ ((row & 7) << 4)));
        }
    #pragma unroll
    for (int tj = 0; tj < 8; ++tj) {
        h8 bf[4];
        #pragma unroll
        for (int ks = 0; ks < 4; ++ks) {
            int row = tj * 16 + l15;
            bf[ks] = *(const h8*)(L + L_KEB + row * 256 + ((ks * 64 + g4 * 16) ^ ((row & 7) << 4)));
        }
        #pragma unroll
        for (int ti = 0; ti < 2; ++ti) {
            f4 c = {0.f, 0.f, 0.f, 0.f};
            #pragma unroll
            for (int ks = 0; ks < 4; ++ks)
                c = __builtin_amdgcn_mfma_f32_16x16x32_f16(af[ti][ks], bf[ks], c, 0, 0, 0);
            acc[ti][tj] = c;
        }
    }
}

// passA: build emb + qk, accumulate sim stats only.
__global__ __launch_bounds__(256, 2) void k_passA(const float* __restrict__ qkv,
                                                  const float* __restrict__ remb,
                                                  float* __restrict__ ws) {
    __shared__ __align__(16) unsigned char L[81920];
    int t = threadIdx.x;
    int lane = t & 63, w = t >> 6;
    int l15 = lane & 15, g4 = lane >> 4;
    int n = blockIdx.x >> 2, g = blockIdx.x & 3;

    stage_aqk(L, qkv, ws, n, g, t);
    stage_ret(L, remb, 0, t);
    __syncthreads();

    float es[4] = {0.f, 0.f, 0.f, 0.f};
    build_emb(L, w, l15, g4, es);
    __syncthreads();

    // stash emb wave-sums (A_k region is dead now)
    float* red = (float*)(L + L_AK);
    #pragma unroll
    for (int k = 0; k < 4; ++k) es[k] = wred(es[k]);
    if (lane == 0) {
        red[w * 4 + 0] = es[0]; red[w * 4 + 1] = es[1];
        red[w * 4 + 2] = es[2]; red[w * 4 + 3] = es[3];
    }

    f4 acc[2][8];
    qk_mfma(L, w * 32, l15, g4, acc);

    float s = 0.f, ss = 0.f;
    #pragma unroll
    for (int ti = 0; ti < 2; ++ti)
        #pragma unroll
        for (int tj = 0; tj < 8; ++tj)
            #pragma unroll
            for (int r = 0; r < 4; ++r) { float x = acc[ti][tj][r]; s += x; ss += x * x; }
    s = wred(s); ss = wred(ss);
    if (lane == 0) { red[16 + w * 2] = s; red[17 + w * 2] = ss; }
    __syncthreads();

    if (t == 0) atomicAdd(&ws[WS_STAT_SIM + g],      red[16] + red[18] + red[20] + red[22]);
    if (t == 1) atomicAdd(&ws[WS_STAT_SIM + 12 + g], red[17] + red[19] + red[21] + red[23]);
    if (t == 2) atomicAdd(&ws[WS_STAT_SIM + 4 + g],  red[0] + red[4] + red[8] + red[12]);
    if (t == 3) atomicAdd(&ws[WS_STAT_SIM + 16 + g], red[1] + red[5] + red[9] + red[13]);
    if (t == 4) atomicAdd(&ws[WS_STAT_SIM + 8 + g],  red[2] + red[6] + red[10] + red[14]);
    if (t == 5) atomicAdd(&ws[WS_STAT_SIM + 20 + g], red[3] + red[7] + red[11] + red[15]);
}

// passB: rebuild, combine+softmax, am (MFMA) + ame (VALU), write att.
__global__ __launch_bounds__(256, 2) void k_passB(const float* __restrict__ qkv,
                                                  const float* __restrict__ remb,
                                                  const float* __restrict__ ws,
                                                  float* __restrict__ att) {
    __shared__ __align__(16) unsigned char L[81920];
    int t = threadIdx.x;
    int lane = t & 63, w = t >> 6;
    int l15 = lane & 15, g4 = lane >> 4;
    int n = blockIdx.x >> 2, g = blockIdx.x & 3;

    stage_aqk(L, qkv, ws, n, g, t);
    stage_ret(L, remb, 0, t);
    __syncthreads();

    float es[4] = {0.f, 0.f, 0.f, 0.f};
    build_emb(L, w, l15, g4, es);
    __syncthreads();

    // stage V (into A_q region) and ve (into reTb region); hidden under qk MFMA
    #pragma unroll
    for (int k = 0; k < 8; ++k) {
        int i = t + k * 256;
        int j = i & 127, c = i >> 7;
        int o = g * 32 + 16 + c;
        float v = ws[WS_COEF_QKV + o] * qkv[n * 16384 + o * 128 + j] + ws[WS_COEF_QKV + 128 + o];
        *(_Float16*)(L + L_V + c * 256 + ((j * 2) ^ ((c & 7) << 4))) = (_Float16)v;
    }
    stage_ret(L, remb, 16, t);

    int i0 = w * 32;
    f4 acc[2][8];
    qk_mfma(L, i0, l15, g4, acc);

    // combine: sim = Aqk*qk + Aqe*Q[i][j] + Ake*K[i][j] + Cst
    float Aqk = ws[WS_COEF_SIM + g], Aqe = ws[WS_COEF_SIM + 4 + g];
    float Ake = ws[WS_COEF_SIM + 8 + g], Cst = ws[WS_COEF_SIM + 12 + g];
    #pragma unroll
    for (int ti = 0; ti < 2; ++ti) {
        int ib = (i0 + ti * 16 + g4 * 4) * 2;
        #pragma unroll
        for (int tj = 0; tj < 8; ++tj) {
            int j = tj * 16 + l15;
            h4 q4 = *(const h4*)(L + L_QEA + j * 256 + (ib ^ ((j & 7) << 4)));
            h4 k4 = *(const h4*)(L + L_KEB + j * 256 + (ib ^ ((j & 7) << 4)));
            #pragma unroll
            for (int r = 0; r < 4; ++r)
                acc[ti][tj][r] = Aqk * acc[ti][tj][r] + Aqe * (float)q4[r] + Ake * (float)k4[r] + Cst;
        }
    }

    // softmax over j, in-register (row i shared by the 16-lane group)
    float inv8[2][4];
    #pragma unroll
    for (int ti = 0; ti < 2; ++ti)
        #pragma unroll
        for (int r = 0; r < 4; ++r) {
            float m = acc[ti][0][r];
            #pragma unroll
            for (int tj = 1; tj < 8; ++tj) m = fmaxf(m, acc[ti][tj][r]);
            #pragma unroll
            for (int msk = 1; msk < 16; msk <<= 1) m = fmaxf(m, __shfl_xor(m, msk, 64));
            float s = 0.f;
            #pragma unroll
            for (int tj = 0; tj < 8; ++tj) {
                float e = __expf(acc[ti][tj][r] - m);
                acc[ti][tj][r] = e; s += e;
            }
            #pragma unroll
            for (int msk = 1; msk < 16; msk <<= 1) s += __shfl_xor(s, msk, 64);
            inv8[ti][r] = 1.f / s;
        }
    __syncthreads();   // everyone done reading qeA/keB

    // write P[i][j] fp16 into qeA region
    #pragma unroll
    for (int ti = 0; ti < 2; ++ti)
        #pragma unroll
        for (int r = 0; r < 4; ++r) {
            int i = i0 + ti * 16 + g4 * 4 + r;
            int swz = (i & 7) << 4;
            float inv = inv8[ti][r];
            #pragma unroll
            for (int tj = 0; tj < 8; ++tj)
                *(_Float16*)(L + L_QEA + i * 256 + ((((tj * 16 + l15) * 2)) ^ swz)) =
                    (_Float16)(acc[ti][tj][r] * inv);
        }
    __syncthreads();

    float* ab = att + n * 16384 + (g * 32) * 128;
    if (w >= 2) {
        // am[c][i] = sum_j V[c][j] * P[i][j]  via MFMA (waves 2,3)
        int itb = (w - 2) * 4;
        h8 vf[4];
        #pragma unroll
        for (int ks = 0; ks < 4; ++ks)
            vf[ks] = *(const h8*)(L + L_V + l15 * 256 + ((ks * 64 + g4 * 16) ^ ((l15 & 7) << 4)));
        #pragma unroll
        for (int it = 0; it < 4; ++it) {
            f4 c4 = {0.f, 0.f, 0.f, 0.f};
            #pragma unroll
            for (int ks = 0; ks < 4; ++ks) {
                int row = (itb + it) * 16 + l15;
                h8 pf = *(const h8*)(L + L_QEA + row * 256 + ((ks * 64 + g4 * 16) ^ ((row & 7) << 4)));
                c4 = __builtin_amdgcn_mfma_f32_16x16x32_f16(vf[ks], pf, c4, 0, 0, 0);
            }
            int i = (itb + it) * 16 + l15;
            #pragma unroll
            for (int r = 0; r < 4; ++r)
                ab[(2 * (g4 * 4 + r)) * 128 + i] = c4[r];
        }
    } else {
        // ame[c][i] = sum_j P[i][j] * remb[16+c][127+i-j]  (waves 0,1)
        int i = w * 64 + lane;
        float amc[16];
        #pragma unroll
        for (int c = 0; c < 16; ++c) amc[c] = 0.f;
        int swz = (i & 7) << 4;
        for (int jc = 0; jc < 16; ++jc) {
            h8 pch = *(const h8*)(L + L_QEA + i * 256 + ((jc * 16) ^ swz));
            #pragma unroll
            for (int e = 0; e < 8; ++e) {
                int j = jc * 8 + e;
                int d = 127 + i - j;
                int dsw = (d & 4) << 2;
                float pf = (float)pch[e];
                h8 r0 = *(const h8*)(L + L_RET + d * 32 + (0 ^ dsw));
                h8 r1 = *(const h8*)(L + L_RET + d * 32 + (16 ^ dsw));
                #pragma unroll
                for (int c = 0; c < 8; ++c) {
                    amc[c]     += pf * (float)r0[c];
                    amc[8 + c] += pf * (float)r1[c];
                }
            }
        }
        #pragma unroll
        for (int c = 0; c < 16; ++c)
            ab[(2 * c + 1) * 128 + i] = amc[c];
    }
}

__global__ void k_prep_sim(const float* __restrict__ g, const float* __restrict__ bta,
                           float* __restrict__ ws) {
    int i = threadIdx.x; if (i >= 4) return;
    float cnt = 8388608.f;
    float aa[3], bb[3];
    for (int k = 0; k < 3; ++k) {
        int ch = k * 4 + i;
        float mean = ws[WS_STAT_SIM + ch] / cnt;
        float var  = ws[WS_STAT_SIM + 12 + ch] / cnt - mean * mean;
        float tt = rsqrtf(var + EPS);
        float A = g[ch] * tt;
        aa[k] = A; bb[k] = bta[ch] - mean * A;
    }
    ws[WS_COEF_SIM + i]      = aa[0];
    ws[WS_COEF_SIM + 4 + i]  = aa[1];
    ws[WS_COEF_SIM + 8 + i]  = aa[2];
    ws[WS_COEF_SIM + 12 + i] = bb[0] + bb[1] + bb[2];
}

__global__ void k_prep_out(const float* __restrict__ g, const float* __restrict__ bta,
                           float* __restrict__ ws) {
    int c = threadIdx.x; if (c >= 128) return;
    float cnt = 65536.f;
    float mean = ws[WS_STAT_OUT + c] / cnt;
    float var  = ws[WS_STAT_OUT + 128 + c] / cnt - mean * mean;
    float tt = rsqrtf(var + EPS);
    float A = g[c] * tt;
    ws[WS_COEF_OUT + c] = A;
    ws[WS_COEF_OUT + 128 + c] = bta[c] - mean * A;
}

// axial0 finish: att[n=b*128+w][ch][h] -> t2[b][c][h][w]
__global__ __launch_bounds__(256) void k_finish0(const float* __restrict__ att,
                                                 const float* __restrict__ ws,
                                                 float* __restrict__ t2) {
    __shared__ float tile[16][32][33];
    int bid = blockIdx.x;
    int wt = bid & 3, ht = (bid >> 2) & 3, cg = (bid >> 4) & 7, b = bid >> 7;
    int t = threadIdx.x;
    for (int i = t; i < 16384; i += 256) {
        int h = i & 31, w = (i >> 5) & 31, cl = i >> 10;
        int c_out = cg * 8 + (cl >> 1), s = cl & 1;
        int chg = (c_out >> 4) * 32 + (c_out & 15) * 2 + s;
        float v = att[((b * 128 + wt * 32 + w) * 128 + chg) * 128 + ht * 32 + h];
        tile[cl][w][h] = ws[WS_COEF_OUT + chg] * v + ws[WS_COEF_OUT + 128 + chg];
    }
    __syncthreads();
    for (int i = t; i < 8192; i += 256) {
        int w = i & 31, h = (i >> 5) & 31, cl = i >> 10;
        float v = tile[2 * cl][w][h] + tile[2 * cl + 1][w][h];
        t2[((b * 64 + cg * 8 + cl) * 128 + ht * 32 + h) * 128 + wt * 32 + w] = v;
    }
}

__global__ void k_zero2(float* __restrict__ ws) {
    int t = threadIdx.x;
    if (t < 256) ws[WS_STAT_QKV + t] = 0.f;
    if (t < 24)  ws[WS_STAT_SIM + t] = 0.f;
    if (t < 256) ws[WS_STAT_OUT + t] = 0.f;
}

// axial1 finish: att[n=b*128+h][ch][w] -> t3[b][c][h][w]
__global__ __launch_bounds__(256) void k_finish1(const float* __restrict__ att,
                                                 const float* __restrict__ ws,
                                                 float* __restrict__ t3) {
    int idx = blockIdx.x * 256 + threadIdx.x;
    int w = idx & 127, h = (idx >> 7) & 127, c = (idx >> 14) & 63, b = idx >> 20;
    int chg = (c >> 4) * 32 + (c & 15) * 2;
    int base = ((b * 128 + h) * 128 + chg) * 128 + w;
    float v0 = att[base], v1 = att[base + 128];
    t3[idx] = ws[WS_COEF_OUT + chg] * v0 + ws[WS_COEF_OUT + 128 + chg]
            + ws[WS_COEF_OUT + chg + 1] * v1 + ws[WS_COEF_OUT + 129 + chg];
}

// avgpool2(t3) then conv
__global__ __launch_bounds__(256) void k_conv2(const float* __restrict__ t3,
                                               const float* __restrict__ w,
                                               float* __restrict__ out) {
    __shared__ float ws_[4096];
    int t = threadIdx.x;
    for (int i = t; i < 4096; i += 256) ws_[i] = w[i];
    __syncthreads();
    int p = blockIdx.x * 256 + t;
    int b = p >> 12, yx = p & 4095, y = yx >> 6, x = yx & 63;
    const float* tp = t3 + b * 1048576 + (2 * y) * 128 + 2 * x;
    float xc[64];
    #pragma unroll
    for (int c = 0; c < 64; ++c) {
        const float* q = tp + c * 16384;
        xc[c] = 0.25f * (q[0] + q[1] + q[128] + q[129]);
    }
    float* op = out + b * 262144 + yx;
    for (int o = 0; o < 64; ++o) {
        float acc = 0.f;
        #pragma unroll
        for (int c = 0; c < 64; ++c) acc += ws_[o * 64 + c] * xc[c];
        op[o * 4096] = acc;
    }
}

__global__ void k_prep_cbn2(const float* __restrict__ g, const float* __restrict__ bta,
                            float* __restrict__ ws) {
    int c = threadIdx.x; if (c >= 64) return;
    float cnt = 16384.f;
    float mean = ws[WS_STAT_C2 + c] / cnt;
    float var  = ws[WS_STAT_C2 + 64 + c] / cnt - mean * mean;
    float tt = rsqrtf(var + EPS);
    float ab = g[c] * tt;
    float sc = ws[WS_SB2 + c], bi = ws[WS_SB2 + 64 + c];
    ws[WS_COEF_C2 + c] = sc * ab;
    ws[WS_COEF_C2 + 64 + c] = sc * (bta[c] - mean * ab) + bi;
}

__global__ __launch_bounds__(256) void k_final(const float* __restrict__ c2out,
                                               const float* __restrict__ input,
                                               const float* __restrict__ ws,
                                               const float* __restrict__ prelu2,
                                               float* __restrict__ out) {
    int idx = blockIdx.x * 256 + threadIdx.x;
    int x = idx & 63, y = (idx >> 6) & 63, o = (idx >> 12) & 63, b = idx >> 18;
    float v = ws[WS_COEF_C2 + o] * c2out[idx] + ws[WS_COEF_C2 + 64 + o];
    const float* ip = input + ((b * 64 + o) * 128 + 2 * y) * 128 + 2 * x;
    v += 0.25f * (ip[0] + ip[1] + ip[128] + ip[129]);
    float s = *prelu2;
    out[idx] = v >= 0.f ? v : s * v;
}

extern "C" void kernel_launch(void* const* d_in, const int* in_sizes, int n_in,
                              void* d_out, int out_size, void* d_ws, size_t ws_size,
                              hipStream_t stream) {
    const float* input    = (const float*)d_in[0];
    const float* latent   = (const float*)d_in[1];
    const float* w_in     = (const float*)d_in[2];
    const float* cbn1_g   = (const float*)d_in[3];
    const float* cbn1_b   = (const float*)d_in[4];
    const float* cbn1_lin = (const float*)d_in[5];
    const float* prelu1   = (const float*)d_in[6];
    const float* ax_qkv_w[2] = {(const float*)d_in[7],  (const float*)d_in[15]};
    const float* ax_qkv_g[2] = {(const float*)d_in[8],  (const float*)d_in[16]};
    const float* ax_qkv_b[2] = {(const float*)d_in[9],  (const float*)d_in[17]};
    const float* ax_sim_g[2] = {(const float*)d_in[10], (const float*)d_in[18]};
    const float* ax_sim_b[2] = {(const float*)d_in[11], (const float*)d_in[19]};
    const float* ax_rel[2]   = {(const float*)d_in[12], (const float*)d_in[20]};
    const float* ax_out_g[2] = {(const float*)d_in[13], (const float*)d_in[21]};
    const float* ax_out_b[2] = {(const float*)d_in[14], (const float*)d_in[22]};
    const float* w_out    = (const float*)d_in[23];
    const float* cbn2_g   = (const float*)d_in[24];
    const float* cbn2_b   = (const float*)d_in[25];
    const float* cbn2_lin = (const float*)d_in[26];
    const float* prelu2   = (const float*)d_in[27];

    float* ws   = (float*)d_ws;
    float* out0 = ws + WS_R1;
    float* t1t  = ws + WS_R1 + 4194304;
    float* att  = ws + WS_R1;
    float* c2o  = ws + WS_R1;
    float* qkv  = ws + WS_R2;
    float* t23  = ws + WS_R3;
    float* dst  = (float*)d_out;

    k_prep0<<<1, 256, 0, stream>>>(cbn1_lin, cbn2_lin, latent, ws);
    k_conv1<<<256, 256, 0, stream>>>(input, w_in, out0);
    k_stats<<<1024, 256, 0, stream>>>(out0, 64, 14, 65536, 16, ws + WS_STAT_C1);
    k_prep_conv1<<<1, 64, 0, stream>>>(cbn1_g, cbn1_b, ws);
    k_t1t<<<4096, 256, 0, stream>>>(out0, t1t, ws, prelu1);

    // axial 0 (n = b*128 + w, a = h)
    k_qkv<<<512, 256, 0, stream>>>(t1t, ax_qkv_w[0], qkv, 1048576, 8192, 128);
    k_stats<<<1024, 256, 0, stream>>>(qkv, 128, 7, 65536, 8, ws + WS_STAT_QKV);
    k_prep_qkv<<<1, 128, 0, stream>>>(ax_qkv_g[0], ax_qkv_b[0], ws);
    k_passA<<<2048, 256, 0, stream>>>(qkv, ax_rel[0], ws);
    k_prep_sim<<<1, 64, 0, stream>>>(ax_sim_g[0], ax_sim_b[0], ws);
    k_passB<<<2048, 256, 0, stream>>>(qkv, ax_rel[0], ws, att);
    k_stats<<<1024, 256, 0, stream>>>(att, 128, 7, 65536, 8, ws + WS_STAT_OUT);
    k_prep_out<<<1, 128, 0, stream>>>(ax_out_g[0], ax_out_b[0], ws);
    k_finish0<<<512, 256, 0, stream>>>(att, ws, t23);
    k_zero2<<<1, 256, 0, stream>>>(ws);

    // axial 1 (n = b*128 + h, a = w)
    k_qkv<<<512, 256, 0, stream>>>(t23, ax_qkv_w[1], qkv, 1048576, 128, 16384);
    k_stats<<<1024, 256, 0, stream>>>(qkv, 128, 7, 65536, 8, ws + WS_STAT_QKV);
    k_prep_qkv<<<1, 128, 0, stream>>>(ax_qkv_g[1], ax_qkv_b[1], ws);
    k_passA<<<2048, 256, 0, stream>>>(qkv, ax_rel[1], ws);
    k_prep_sim<<<1, 64, 0, stream>>>(ax_sim_g[1], ax_sim_b[1], ws);
    k_passB<<<2048, 256, 0, stream>>>(qkv, ax_rel[1], ws, att);
    k_stats<<<1024, 256, 0, stream>>>(att, 128, 7, 65536, 8, ws + WS_STAT_OUT);
    k_prep_out<<<1, 128, 0, stream>>>(ax_out_g[1], ax_out_b[1], ws);
    k_finish1<<<16384, 256, 0, stream>>>(att, ws, t23);

    k_conv2<<<64, 256, 0, stream>>>(t23, w_out, c2o);
    k_stats<<<256, 256, 0, stream>>>(c2o, 64, 12, 16384, 4, ws + WS_STAT_C2);
    k_prep_cbn2<<<1, 64, 0, stream>>>(cbn2_g, cbn2_b, ws);
    k_final<<<4096, 256, 0, stream>>>(c2o, input, ws, prelu2, dst);
}

// Round 3
// 726.312 us; speedup vs baseline: 2.8472x; 1.1249x over previous
//
#include <hip/hip_runtime.h>

#define EPS 1e-5f

typedef __attribute__((ext_vector_type(4))) _Float16 h4;
typedef __attribute__((ext_vector_type(8))) _Float16 h8;
typedef __attribute__((ext_vector_type(4))) float f4;

// ---- workspace float offsets (params/stats region) ----
#define WS_SB1      0
#define WS_SB2      128
#define WS_STAT_C1  256
#define WS_COEF_C1  384
#define WS_STAT_QKV 512
#define WS_COEF_QKV 768
#define WS_STAT_SIM 1024
#define WS_COEF_SIM 1056
#define WS_STAT_OUT 1088
#define WS_COEF_OUT 1344
#define WS_STAT_C2  1600
#define WS_COEF_C2  1728
#define WS_STAT_END 1856

// ---- buffer regions (float offsets) ----
#define WS_R1  4096
#define WS_R2  (WS_R1 + 8388608)
#define WS_R3  (WS_R2 + 8388608)

// ---- pass-kernel LDS byte offsets (80 KiB -> 2 blocks/CU) ----
#define L_QEA 0        // [128 b][128 a] fp16 swz ^((b&7)<<4); later P[i][j]
#define L_KEB 32768    // k_emb same layout; later Pd half [128 i][128 col]
#define L_RET 65536    // build: re [256 d][16 c] swz ^((d&4)<<2); later ve [16 c][256 d] swz ^((c&7)<<4)
#define L_AQ  73728    // q [128 a][16 c]; later V [16 c][128 j] swz ^((c&7)<<4)
#define L_AK  77824    // k rows 8-15; passA: f32 red[] scratch
#define L_V   73728

__device__ __forceinline__ float wred(float v) {
    #pragma unroll
    for (int off = 32; off > 0; off >>= 1) v += __shfl_down(v, off, 64);
    return v;
}

__global__ void k_prep0(const float* __restrict__ lin1, const float* __restrict__ lin2,
                        const float* __restrict__ latent, float* __restrict__ ws) {
    int t = threadIdx.x;
    for (int i = 256 + t; i < WS_STAT_END; i += 256) ws[i] = 0.f;
    const float* lin = (t < 128) ? lin1 : lin2;
    int row = t & 127;
    float s = 0.f;
    for (int l = 0; l < 256; ++l) s += lin[row * 256 + l] * latent[l];
    ws[(t < 128 ? WS_SB1 : WS_SB2) + row] = s;
}

__global__ __launch_bounds__(256) void k_conv1(const float* __restrict__ in,
                                               const float* __restrict__ w,
                                               float* __restrict__ out) {
    __shared__ float ws_[4096];
    int t = threadIdx.x;
    for (int i = t; i < 4096; i += 256) ws_[i] = w[i];
    __syncthreads();
    int p  = blockIdx.x * 256 + t;
    int b  = p >> 14, hw = p & 16383;
    const float* ip = in + b * 64 * 16384 + hw;
    float x[64];
    #pragma unroll
    for (int c = 0; c < 64; ++c) x[c] = ip[c * 16384];
    float* op = out + b * 64 * 16384 + hw;
    for (int o = 0; o < 64; ++o) {
        float acc = 0.f;
        #pragma unroll
        for (int c = 0; c < 64; ++c) acc += ws_[o * 64 + c] * x[c];
        op[o * 16384] = acc;
    }
}

__global__ void k_stats(const float* __restrict__ src, int C, int logK, int MK, int split,
                        float* __restrict__ stat) {
    int c = blockIdx.x % C;
    int chunk = blockIdx.x / C;
    int per = MK / split;
    int base = chunk * per;
    int Km1 = (1 << logK) - 1;
    float s = 0.f, ss = 0.f;
    for (int i = base + threadIdx.x; i < base + per; i += blockDim.x) {
        int m = i >> logK, k = i & Km1;
        float v = src[((m * C + c) << logK) + k];
        s += v; ss += v * v;
    }
    s = wred(s); ss = wred(ss);
    if ((threadIdx.x & 63) == 0) { atomicAdd(&stat[c], s); atomicAdd(&stat[C + c], ss); }
}

__global__ void k_prep_conv1(const float* __restrict__ g, const float* __restrict__ bta,
                             float* __restrict__ ws) {
    int c = threadIdx.x; if (c >= 64) return;
    float cnt = 65536.f;
    float mean = ws[WS_STAT_C1 + c] / cnt;
    float var  = ws[WS_STAT_C1 + 64 + c] / cnt - mean * mean;
    float tt = rsqrtf(var + EPS);
    float ab = g[c] * tt;
    float sc = ws[WS_SB1 + c], bi = ws[WS_SB1 + 64 + c];
    ws[WS_COEF_C1 + c] = sc * ab;
    ws[WS_COEF_C1 + 64 + c] = sc * (bta[c] - mean * ab) + bi;
}

__global__ __launch_bounds__(256) void k_t1t(const float* __restrict__ src, float* __restrict__ dst,
                                             const float* __restrict__ ws,
                                             const float* __restrict__ prelu1) {
    __shared__ float tile[32][33];
    int bid = blockIdx.x;
    int wt = bid & 3, ht = (bid >> 2) & 3, c = (bid >> 4) & 63, b = bid >> 10;
    float A = ws[WS_COEF_C1 + c], Bb = ws[WS_COEF_C1 + 64 + c];
    float slope = *prelu1;
    int tx = threadIdx.x & 31, ty = threadIdx.x >> 5;
    const float* sp = src + ((b * 64 + c) * 128 + ht * 32) * 128 + wt * 32;
    for (int r = 0; r < 4; ++r) {
        float v = sp[(ty + r * 8) * 128 + tx];
        v = A * v + Bb;
        v = v >= 0.f ? v : slope * v;
        tile[ty + r * 8][tx] = v;
    }
    __syncthreads();
    float* dp = dst + b * 1048576 + (wt * 32) * 8192 + c * 128 + ht * 32;
    for (int r = 0; r < 4; ++r)
        dp[(ty + r * 8) * 8192 + tx] = tile[tx][ty + r * 8];
}

__global__ __launch_bounds__(256) void k_qkv(const float* __restrict__ x, const float* __restrict__ w,
                                             float* __restrict__ out, int SB, int SR, int SC) {
    __shared__ float ws_[8192];
    __shared__ float xs[64][128];
    int t = threadIdx.x;
    for (int i = t; i < 8192; i += 256) ws_[i] = w[i];
    int n = blockIdx.x;
    int b = n >> 7, r = n & 127;
    const float* xp = x + b * SB + r * SR;
    for (int i = t; i < 8192; i += 256) {
        int c = i >> 7, a = i & 127;
        xs[c][a] = xp[c * SC + a];
    }
    __syncthreads();
    int a = t & 127, oh = t >> 7;
    float xc[64];
    #pragma unroll
    for (int c = 0; c < 64; ++c) xc[c] = xs[c][a];
    float* op = out + n * 16384 + oh * 8192 + a;
    for (int o = 0; o < 64; ++o) {
        const float* wr = &ws_[(oh * 64 + o) * 64];
        float acc = 0.f;
        #pragma unroll
        for (int c = 0; c < 64; ++c) acc += wr[c] * xc[c];
        op[o * 128] = acc;
    }
}

__global__ void k_prep_qkv(const float* __restrict__ g, const float* __restrict__ bta,
                           float* __restrict__ ws) {
    int c = threadIdx.x; if (c >= 128) return;
    float cnt = 65536.f;
    float mean = ws[WS_STAT_QKV + c] / cnt;
    float var  = ws[WS_STAT_QKV + 128 + c] / cnt - mean * mean;
    float tt = rsqrtf(var + EPS);
    float A = g[c] * tt;
    ws[WS_COEF_QKV + c] = A;
    ws[WS_COEF_QKV + 128 + c] = bta[c] - mean * A;
}

// ---- shared device helpers for passes ----
__device__ __forceinline__ void stage_aqk(unsigned char* L, const float* qkv, const float* ws,
                                          int n, int g, int t) {
    const float* qp = qkv + n * 16384 + g * 32 * 128;
    #pragma unroll
    for (int k = 0; k < 8; ++k) {
        int i = t + k * 256;
        int a = i & 127, cc = i >> 7;
        float v = ws[WS_COEF_QKV + g * 32 + cc] * qp[cc * 128 + a] + ws[WS_COEF_QKV + 128 + g * 32 + cc];
        _Float16 h = (_Float16)v;
        int off = a * 32 + ((cc * 2) ^ ((a & 4) << 2));
        *(_Float16*)(L + L_AQ + off) = (cc < 8) ? h : (_Float16)0.f;
        *(_Float16*)(L + L_AK + off) = (cc < 8) ? (_Float16)0.f : h;
    }
}

__device__ __forceinline__ void stage_ret(unsigned char* L, const float* remb, int crow0, int t) {
    #pragma unroll
    for (int k = 0; k < 16; ++k) {
        int i = t + k * 256;
        int d = i & 255, c = i >> 8;
        float v = (d < 255) ? remb[(crow0 + c) * 255 + d] : 0.f;
        *(_Float16*)(L + L_RET + d * 32 + ((c * 2) ^ ((d & 4) << 2))) = (_Float16)v;
    }
}

// build q_emb/k_emb via diag-MFMA, band-trimmed to useful d tiles (9 of 16)
__device__ __forceinline__ void build_emb(unsigned char* L, int w, int l15, int g4, float* s) {
    #pragma unroll
    for (int ah = 0; ah < 2; ++ah) {
        int at = w * 2 + ah;
        int arow = at * 16 + l15;
        int aoff = arow * 32 + ((g4 * 8) ^ ((arow & 4) << 2));
        h4 aq = *(const h4*)(L + L_AQ + aoff);
        h4 ak = *(const h4*)(L + L_AK + aoff);
        int abase = at * 16 + g4 * 4;
        for (int m = 0; m < 9; ++m) {
            int drow = (at + m) * 16 + l15;
            h4 bf = *(const h4*)(L + L_RET + drow * 32 + ((g4 * 8) ^ ((drow & 4) << 2)));
            f4 z = {0.f, 0.f, 0.f, 0.f};
            f4 dq = __builtin_amdgcn_mfma_f32_16x16x16f16(aq, bf, z, 0, 0, 0);
            f4 dk = __builtin_amdgcn_mfma_f32_16x16x16f16(ak, bf, z, 0, 0, 0);
            #pragma unroll
            for (int r = 0; r < 4; ++r) {
                int a = abase + r;
                int b = 127 + a - drow;
                if (b >= 0 && b < 128) {
                    int off = b * 256 + ((a * 2) ^ ((b & 7) << 4));
                    *(_Float16*)(L + L_QEA + off) = (_Float16)dq[r];
                    *(_Float16*)(L + L_KEB + off) = (_Float16)dk[r];
                    s[0] += dq[r]; s[1] += dq[r] * dq[r];
                    s[2] += dk[r]; s[3] += dk[r] * dk[r];
                }
            }
        }
    }
}

__device__ __forceinline__ void qk_mfma(unsigned char* L, int i0, int l15, int g4, f4 acc[2][8]) {
    h8 af[2][4];
    #pragma unroll
    for (int ti = 0; ti < 2; ++ti)
        #pragma unroll
        for (int ks = 0; ks < 4; ++ks) {
            int row = i0 + ti * 16 + l15;
            af[ti][ks] = *(const h8*)(L + L_QEA + row * 256 + ((ks * 64 + g4 * 16) ^ ((row & 7) << 4)));
        }
    #pragma unroll
    for (int tj = 0; tj < 8; ++tj) {
        h8 bf[4];
        #pragma unroll
        for (int ks = 0; ks < 4; ++ks) {
            int row = tj * 16 + l15;
            bf[ks] = *(const h8*)(L + L_KEB + row * 256 + ((ks * 64 + g4 * 16) ^ ((row & 7) << 4)));
        }
        #pragma unroll
        for (int ti = 0; ti < 2; ++ti) {
            f4 c = {0.f, 0.f, 0.f, 0.f};
            #pragma unroll
            for (int ks = 0; ks < 4; ++ks)
                c = __builtin_amdgcn_mfma_f32_16x16x32_f16(af[ti][ks], bf[ks], c, 0, 0, 0);
            acc[ti][tj] = c;
        }
    }
}

// passA: build emb + qk, accumulate sim stats only.
__global__ __launch_bounds__(256, 2) void k_passA(const float* __restrict__ qkv,
                                                  const float* __restrict__ remb,
                                                  float* __restrict__ ws) {
    __shared__ __align__(16) unsigned char L[81920];
    int t = threadIdx.x;
    int lane = t & 63, w = t >> 6;
    int l15 = lane & 15, g4 = lane >> 4;
    int n = blockIdx.x >> 2, g = blockIdx.x & 3;

    stage_aqk(L, qkv, ws, n, g, t);
    stage_ret(L, remb, 0, t);
    __syncthreads();

    float es[4] = {0.f, 0.f, 0.f, 0.f};
    build_emb(L, w, l15, g4, es);
    __syncthreads();

    float* red = (float*)(L + L_AK);
    #pragma unroll
    for (int k = 0; k < 4; ++k) es[k] = wred(es[k]);
    if (lane == 0) {
        red[w * 4 + 0] = es[0]; red[w * 4 + 1] = es[1];
        red[w * 4 + 2] = es[2]; red[w * 4 + 3] = es[3];
    }

    f4 acc[2][8];
    qk_mfma(L, w * 32, l15, g4, acc);

    float s = 0.f, ss = 0.f;
    #pragma unroll
    for (int ti = 0; ti < 2; ++ti)
        #pragma unroll
        for (int tj = 0; tj < 8; ++tj)
            #pragma unroll
            for (int r = 0; r < 4; ++r) { float x = acc[ti][tj][r]; s += x; ss += x * x; }
    s = wred(s); ss = wred(ss);
    if (lane == 0) { red[16 + w * 2] = s; red[17 + w * 2] = ss; }
    __syncthreads();

    if (t == 0) atomicAdd(&ws[WS_STAT_SIM + g],      red[16] + red[18] + red[20] + red[22]);
    if (t == 1) atomicAdd(&ws[WS_STAT_SIM + 12 + g], red[17] + red[19] + red[21] + red[23]);
    if (t == 2) atomicAdd(&ws[WS_STAT_SIM + 4 + g],  red[0] + red[4] + red[8] + red[12]);
    if (t == 3) atomicAdd(&ws[WS_STAT_SIM + 16 + g], red[1] + red[5] + red[9] + red[13]);
    if (t == 4) atomicAdd(&ws[WS_STAT_SIM + 8 + g],  red[2] + red[6] + red[10] + red[14]);
    if (t == 5) atomicAdd(&ws[WS_STAT_SIM + 20 + g], red[3] + red[7] + red[11] + red[15]);
}

// passB: rebuild, combine+softmax, am + ame both via MFMA over all 4 waves.
__global__ __launch_bounds__(256, 2) void k_passB(const float* __restrict__ qkv,
                                                  const float* __restrict__ remb,
                                                  const float* __restrict__ ws,
                                                  float* __restrict__ att) {
    __shared__ __align__(16) unsigned char L[81920];
    int t = threadIdx.x;
    int lane = t & 63, w = t >> 6;
    int l15 = lane & 15, g4 = lane >> 4;
    int n = blockIdx.x >> 2, g = blockIdx.x & 3;

    stage_aqk(L, qkv, ws, n, g, t);
    stage_ret(L, remb, 0, t);
    __syncthreads();

    float es[4] = {0.f, 0.f, 0.f, 0.f};
    build_emb(L, w, l15, g4, es);
    __syncthreads();

    // stage V [16 c][128 j] into L_V; ve [16 c][256 d] into L_RET (both dead regions)
    #pragma unroll
    for (int k = 0; k < 8; ++k) {
        int i = t + k * 256;
        int j = i & 127, c = i >> 7;
        int o = g * 32 + 16 + c;
        float v = ws[WS_COEF_QKV + o] * qkv[n * 16384 + o * 128 + j] + ws[WS_COEF_QKV + 128 + o];
        *(_Float16*)(L + L_V + c * 256 + ((j * 2) ^ ((c & 7) << 4))) = (_Float16)v;
    }
    #pragma unroll
    for (int k = 0; k < 16; ++k) {
        int i = t + k * 256;
        int d = i & 255, c = i >> 8;
        float v = (d < 255) ? remb[(16 + c) * 255 + d] : 0.f;
        *(_Float16*)(L + L_RET + c * 512 + ((d * 2) ^ ((c & 7) << 4))) = (_Float16)v;
    }

    int i0 = w * 32;
    f4 acc[2][8];
    qk_mfma(L, i0, l15, g4, acc);

    float Aqk = ws[WS_COEF_SIM + g], Aqe = ws[WS_COEF_SIM + 4 + g];
    float Ake = ws[WS_COEF_SIM + 8 + g], Cst = ws[WS_COEF_SIM + 12 + g];
    #pragma unroll
    for (int ti = 0; ti < 2; ++ti) {
        int ib = (i0 + ti * 16 + g4 * 4) * 2;
        #pragma unroll
        for (int tj = 0; tj < 8; ++tj) {
            int j = tj * 16 + l15;
            h4 q4 = *(const h4*)(L + L_QEA + j * 256 + (ib ^ ((j & 7) << 4)));
            h4 k4 = *(const h4*)(L + L_KEB + j * 256 + (ib ^ ((j & 7) << 4)));
            #pragma unroll
            for (int r = 0; r < 4; ++r)
                acc[ti][tj][r] = Aqk * acc[ti][tj][r] + Aqe * (float)q4[r] + Ake * (float)k4[r] + Cst;
        }
    }

    // softmax over j, in-register
    float inv8[2][4];
    #pragma unroll
    for (int ti = 0; ti < 2; ++ti)
        #pragma unroll
        for (int r = 0; r < 4; ++r) {
            float m = acc[ti][0][r];
            #pragma unroll
            for (int tj = 1; tj < 8; ++tj) m = fmaxf(m, acc[ti][tj][r]);
            #pragma unroll
            for (int msk = 1; msk < 16; msk <<= 1) m = fmaxf(m, __shfl_xor(m, msk, 64));
            float s = 0.f;
            #pragma unroll
            for (int tj = 0; tj < 8; ++tj) {
                float e = __expf(acc[ti][tj][r] - m);
                acc[ti][tj][r] = e; s += e;
            }
            #pragma unroll
            for (int msk = 1; msk < 16; msk <<= 1) s += __shfl_xor(s, msk, 64);
            inv8[ti][r] = 1.f / s;
        }
    __syncthreads();   // all reads of qeA/keB (combine) done

    // write P[i][j] -> QEA ; Pd-low half -> KEB (full coverage incl. zeros)
    #pragma unroll
    for (int ti = 0; ti < 2; ++ti)
        #pragma unroll
        for (int r = 0; r < 4; ++r) {
            int i = i0 + ti * 16 + g4 * 4 + r;
            int swz = (i & 7) << 4;
            float inv = inv8[ti][r];
            #pragma unroll
            for (int tj = 0; tj < 8; ++tj) {
                int j = tj * 16 + l15;
                _Float16 h = (_Float16)(acc[ti][tj][r] * inv);
                *(_Float16*)(L + L_QEA + i * 256 + ((j * 2) ^ swz)) = h;
                int cl = (j >= i) ? (127 + i - j) : j;
                *(_Float16*)(L + L_KEB + i * 256 + ((cl * 2) ^ swz)) = (j >= i) ? h : (_Float16)0.f;
            }
        }
    __syncthreads();

    // am (from P) + ame phase 1 (from Pd-low), 2 i-tiles per wave
    h8 vf[4], vef[4];
    #pragma unroll
    for (int ks = 0; ks < 4; ++ks) {
        vf[ks]  = *(const h8*)(L + L_V   + l15 * 256 + ((ks * 64 + g4 * 16) ^ ((l15 & 7) << 4)));
        vef[ks] = *(const h8*)(L + L_RET + l15 * 512 + ((ks * 64 + g4 * 16) ^ ((l15 & 7) << 4)));
    }
    f4 cam[2], cae[2];
    #pragma unroll
    for (int it2 = 0; it2 < 2; ++it2) {
        int row = (w * 2 + it2) * 16 + l15;
        int sw = (row & 7) << 4;
        f4 a1 = {0.f, 0.f, 0.f, 0.f}, a2 = {0.f, 0.f, 0.f, 0.f};
        #pragma unroll
        for (int ks = 0; ks < 4; ++ks) {
            h8 pf  = *(const h8*)(L + L_QEA + row * 256 + ((ks * 64 + g4 * 16) ^ sw));
            h8 plf = *(const h8*)(L + L_KEB + row * 256 + ((ks * 64 + g4 * 16) ^ sw));
            a1 = __builtin_amdgcn_mfma_f32_16x16x32_f16(vf[ks],  pf,  a1, 0, 0, 0);
            a2 = __builtin_amdgcn_mfma_f32_16x16x32_f16(vef[ks], plf, a2, 0, 0, 0);
        }
        cam[it2] = a1; cae[it2] = a2;
    }
    __syncthreads();

    // write Pd-high half -> KEB (full coverage incl. zeros)
    #pragma unroll
    for (int ti = 0; ti < 2; ++ti)
        #pragma unroll
        for (int r = 0; r < 4; ++r) {
            int i = i0 + ti * 16 + g4 * 4 + r;
            int swz = (i & 7) << 4;
            float inv = inv8[ti][r];
            #pragma unroll
            for (int tj = 0; tj < 8; ++tj) {
                int j = tj * 16 + l15;
                _Float16 h = (_Float16)(acc[ti][tj][r] * inv);
                int cl = (j < i) ? (i - 1 - j) : j;
                *(_Float16*)(L + L_KEB + i * 256 + ((cl * 2) ^ swz)) = (j < i) ? h : (_Float16)0.f;
            }
        }
    __syncthreads();

    // ame phase 2 (ve cols 128..255)
    h8 vef2[4];
    #pragma unroll
    for (int ks = 0; ks < 4; ++ks)
        vef2[ks] = *(const h8*)(L + L_RET + l15 * 512 + ((256 + ks * 64 + g4 * 16) ^ ((l15 & 7) << 4)));
    #pragma unroll
    for (int it2 = 0; it2 < 2; ++it2) {
        int row = (w * 2 + it2) * 16 + l15;
        int sw = (row & 7) << 4;
        f4 a2 = cae[it2];
        #pragma unroll
        for (int ks = 0; ks < 4; ++ks) {
            h8 phf = *(const h8*)(L + L_KEB + row * 256 + ((ks * 64 + g4 * 16) ^ sw));
            a2 = __builtin_amdgcn_mfma_f32_16x16x32_f16(vef2[ks], phf, a2, 0, 0, 0);
        }
        cae[it2] = a2;
    }

    float* ab = att + n * 16384 + (g * 32) * 128;
    #pragma unroll
    for (int it2 = 0; it2 < 2; ++it2) {
        int i = (w * 2 + it2) * 16 + l15;
        #pragma unroll
        for (int r = 0; r < 4; ++r) {
            int c = g4 * 4 + r;
            ab[(2 * c) * 128 + i]     = cam[it2][r];
            ab[(2 * c + 1) * 128 + i] = cae[it2][r];
        }
    }
}

__global__ void k_prep_sim(const float* __restrict__ g, const float* __restrict__ bta,
                           float* __restrict__ ws) {
    int i = threadIdx.x; if (i >= 4) return;
    float cnt = 8388608.f;
    float aa[3], bb[3];
    for (int k = 0; k < 3; ++k) {
        int ch = k * 4 + i;
        float mean = ws[WS_STAT_SIM + ch] / cnt;
        float var  = ws[WS_STAT_SIM + 12 + ch] / cnt - mean * mean;
        float tt = rsqrtf(var + EPS);
        float A = g[ch] * tt;
        aa[k] = A; bb[k] = bta[ch] - mean * A;
    }
    ws[WS_COEF_SIM + i]      = aa[0];
    ws[WS_COEF_SIM + 4 + i]  = aa[1];
    ws[WS_COEF_SIM + 8 + i]  = aa[2];
    ws[WS_COEF_SIM + 12 + i] = bb[0] + bb[1] + bb[2];
}

__global__ void k_prep_out(const float* __restrict__ g, const float* __restrict__ bta,
                           float* __restrict__ ws) {
    int c = threadIdx.x; if (c >= 128) return;
    float cnt = 65536.f;
    float mean = ws[WS_STAT_OUT + c] / cnt;
    float var  = ws[WS_STAT_OUT + 128 + c] / cnt - mean * mean;
    float tt = rsqrtf(var + EPS);
    float A = g[c] * tt;
    ws[WS_COEF_OUT + c] = A;
    ws[WS_COEF_OUT + 128 + c] = bta[c] - mean * A;
}

__global__ __launch_bounds__(256) void k_finish0(const float* __restrict__ att,
                                                 const float* __restrict__ ws,
                                                 float* __restrict__ t2) {
    __shared__ float tile[16][32][33];
    int bid = blockIdx.x;
    int wt = bid & 3, ht = (bid >> 2) & 3, cg = (bid >> 4) & 7, b = bid >> 7;
    int t = threadIdx.x;
    for (int i = t; i < 16384; i += 256) {
        int h = i & 31, w = (i >> 5) & 31, cl = i >> 10;
        int c_out = cg * 8 + (cl >> 1), s = cl & 1;
        int chg = (c_out >> 4) * 32 + (c_out & 15) * 2 + s;
        float v = att[((b * 128 + wt * 32 + w) * 128 + chg) * 128 + ht * 32 + h];
        tile[cl][w][h] = ws[WS_COEF_OUT + chg] * v + ws[WS_COEF_OUT + 128 + chg];
    }
    __syncthreads();
    for (int i = t; i < 8192; i += 256) {
        int w = i & 31, h = (i >> 5) & 31, cl = i >> 10;
        float v = tile[2 * cl][w][h] + tile[2 * cl + 1][w][h];
        t2[((b * 64 + cg * 8 + cl) * 128 + ht * 32 + h) * 128 + wt * 32 + w] = v;
    }
}

__global__ void k_zero2(float* __restrict__ ws) {
    int t = threadIdx.x;
    if (t < 256) ws[WS_STAT_QKV + t] = 0.f;
    if (t < 24)  ws[WS_STAT_SIM + t] = 0.f;
    if (t < 256) ws[WS_STAT_OUT + t] = 0.f;
}

__global__ __launch_bounds__(256) void k_finish1(const float* __restrict__ att,
                                                 const float* __restrict__ ws,
                                                 float* __restrict__ t3) {
    int idx = blockIdx.x * 256 + threadIdx.x;
    int w = idx & 127, h = (idx >> 7) & 127, c = (idx >> 14) & 63, b = idx >> 20;
    int chg = (c >> 4) * 32 + (c & 15) * 2;
    int base = ((b * 128 + h) * 128 + chg) * 128 + w;
    float v0 = att[base], v1 = att[base + 128];
    t3[idx] = ws[WS_COEF_OUT + chg] * v0 + ws[WS_COEF_OUT + 128 + chg]
            + ws[WS_COEF_OUT + chg + 1] * v1 + ws[WS_COEF_OUT + 129 + chg];
}

__global__ __launch_bounds__(256) void k_conv2(const float* __restrict__ t3,
                                               const float* __restrict__ w,
                                               float* __restrict__ out) {
    __shared__ float ws_[4096];
    int t = threadIdx.x;
    for (int i = t; i < 4096; i += 256) ws_[i] = w[i];
    __syncthreads();
    int p = blockIdx.x * 256 + t;
    int b = p >> 12, yx = p & 4095, y = yx >> 6, x = yx & 63;
    const float* tp = t3 + b * 1048576 + (2 * y) * 128 + 2 * x;
    float xc[64];
    #pragma unroll
    for (int c = 0; c < 64; ++c) {
        const float* q = tp + c * 16384;
        xc[c] = 0.25f * (q[0] + q[1] + q[128] + q[129]);
    }
    float* op = out + b * 262144 + yx;
    for (int o = 0; o < 64; ++o) {
        float acc = 0.f;
        #pragma unroll
        for (int c = 0; c < 64; ++c) acc += ws_[o * 64 + c] * xc[c];
        op[o * 4096] = acc;
    }
}

__global__ void k_prep_cbn2(const float* __restrict__ g, const float* __restrict__ bta,
                            float* __restrict__ ws) {
    int c = threadIdx.x; if (c >= 64) return;
    float cnt = 16384.f;
    float mean = ws[WS_STAT_C2 + c] / cnt;
    float var  = ws[WS_STAT_C2 + 64 + c] / cnt - mean * mean;
    float tt = rsqrtf(var + EPS);
    float ab = g[c] * tt;
    float sc = ws[WS_SB2 + c], bi = ws[WS_SB2 + 64 + c];
    ws[WS_COEF_C2 + c] = sc * ab;
    ws[WS_COEF_C2 + 64 + c] = sc * (bta[c] - mean * ab) + bi;
}

__global__ __launch_bounds__(256) void k_final(const float* __restrict__ c2out,
                                               const float* __restrict__ input,
                                               const float* __restrict__ ws,
                                               const float* __restrict__ prelu2,
                                               float* __restrict__ out) {
    int idx = blockIdx.x * 256 + threadIdx.x;
    int x = idx & 63, y = (idx >> 6) & 63, o = (idx >> 12) & 63, b = idx >> 18;
    float v = ws[WS_COEF_C2 + o] * c2out[idx] + ws[WS_COEF_C2 + 64 + o];
    const float* ip = input + ((b * 64 + o) * 128 + 2 * y) * 128 + 2 * x;
    v += 0.25f * (ip[0] + ip[1] + ip[128] + ip[129]);
    float s = *prelu2;
    out[idx] = v >= 0.f ? v : s * v;
}

extern "C" void kernel_launch(void* const* d_in, const int* in_sizes, int n_in,
                              void* d_out, int out_size, void* d_ws, size_t ws_size,
                              hipStream_t stream) {
    const float* input    = (const float*)d_in[0];
    const float* latent   = (const float*)d_in[1];
    const float* w_in     = (const float*)d_in[2];
    const float* cbn1_g   = (const float*)d_in[3];
    const float* cbn1_b   = (const float*)d_in[4];
    const float* cbn1_lin = (const float*)d_in[5];
    const float* prelu1   = (const float*)d_in[6];
    const float* ax_qkv_w[2] = {(const float*)d_in[7],  (const float*)d_in[15]};
    const float* ax_qkv_g[2] = {(const float*)d_in[8],  (const float*)d_in[16]};
    const float* ax_qkv_b[2] = {(const float*)d_in[9],  (const float*)d_in[17]};
    const float* ax_sim_g[2] = {(const float*)d_in[10], (const float*)d_in[18]};
    const float* ax_sim_b[2] = {(const float*)d_in[11], (const float*)d_in[19]};
    const float* ax_rel[2]   = {(const float*)d_in[12], (const float*)d_in[20]};
    const float* ax_out_g[2] = {(const float*)d_in[13], (const float*)d_in[21]};
    const float* ax_out_b[2] = {(const float*)d_in[14], (const float*)d_in[22]};
    const float* w_out    = (const float*)d_in[23];
    const float* cbn2_g   = (const float*)d_in[24];
    const float* cbn2_b   = (const float*)d_in[25];
    const float* cbn2_lin = (const float*)d_in[26];
    const float* prelu2   = (const float*)d_in[27];

    float* ws   = (float*)d_ws;
    float* out0 = ws + WS_R1;
    float* t1t  = ws + WS_R1 + 4194304;
    float* att  = ws + WS_R1;
    float* c2o  = ws + WS_R1;
    float* qkv  = ws + WS_R2;
    float* t23  = ws + WS_R3;
    float* dst  = (float*)d_out;

    k_prep0<<<1, 256, 0, stream>>>(cbn1_lin, cbn2_lin, latent, ws);
    k_conv1<<<256, 256, 0, stream>>>(input, w_in, out0);
    k_stats<<<1024, 256, 0, stream>>>(out0, 64, 14, 65536, 16, ws + WS_STAT_C1);
    k_prep_conv1<<<1, 64, 0, stream>>>(cbn1_g, cbn1_b, ws);
    k_t1t<<<4096, 256, 0, stream>>>(out0, t1t, ws, prelu1);

    // axial 0 (n = b*128 + w, a = h)
    k_qkv<<<512, 256, 0, stream>>>(t1t, ax_qkv_w[0], qkv, 1048576, 8192, 128);
    k_stats<<<1024, 256, 0, stream>>>(qkv, 128, 7, 65536, 8, ws + WS_STAT_QKV);
    k_prep_qkv<<<1, 128, 0, stream>>>(ax_qkv_g[0], ax_qkv_b[0], ws);
    k_passA<<<2048, 256, 0, stream>>>(qkv, ax_rel[0], ws);
    k_prep_sim<<<1, 64, 0, stream>>>(ax_sim_g[0], ax_sim_b[0], ws);
    k_passB<<<2048, 256, 0, stream>>>(qkv, ax_rel[0], ws, att);
    k_stats<<<1024, 256, 0, stream>>>(att, 128, 7, 65536, 8, ws + WS_STAT_OUT);
    k_prep_out<<<1, 128, 0, stream>>>(ax_out_g[0], ax_out_b[0], ws);
    k_finish0<<<512, 256, 0, stream>>>(att, ws, t23);
    k_zero2<<<1, 256, 0, stream>>>(ws);

    // axial 1 (n = b*128 + h, a = w)
    k_qkv<<<512, 256, 0, stream>>>(t23, ax_qkv_w[1], qkv, 1048576, 128, 16384);
    k_stats<<<1024, 256, 0, stream>>>(qkv, 128, 7, 65536, 8, ws + WS_STAT_QKV);
    k_prep_qkv<<<1, 128, 0, stream>>>(ax_qkv_g[1], ax_qkv_b[1], ws);
    k_passA<<<2048, 256, 0, stream>>>(qkv, ax_rel[1], ws);
    k_prep_sim<<<1, 64, 0, stream>>>(ax_sim_g[1], ax_sim_b[1], ws);
    k_passB<<<2048, 256, 0, stream>>>(qkv, ax_rel[1], ws, att);
    k_stats<<<1024, 256, 0, stream>>>(att, 128, 7, 65536, 8, ws + WS_STAT_OUT);
    k_prep_out<<<1, 128, 0, stream>>>(ax_out_g[1], ax_out_b[1], ws);
    k_finish1<<<16384, 256, 0, stream>>>(att, ws, t23);

    k_conv2<<<64, 256, 0, stream>>>(t23, w_out, c2o);
    k_stats<<<256, 256, 0, stream>>>(c2o, 64, 12, 16384, 4, ws + WS_STAT_C2);
    k_prep_cbn2<<<1, 64, 0, stream>>>(cbn2_g, cbn2_b, ws);
    k_final<<<4096, 256, 0, stream>>>(c2o, input, ws, prelu2, dst);
}

// Round 4
// 548.890 us; speedup vs baseline: 3.7676x; 1.3232x over previous
//
#include <hip/hip_runtime.h>

#define EPS 1e-5f

typedef __attribute__((ext_vector_type(4))) _Float16 h4;
typedef __attribute__((ext_vector_type(8))) _Float16 h8;
typedef __attribute__((ext_vector_type(4))) float f4;

// ---- workspace float offsets (params/stats region) ----
#define WS_SB1      0
#define WS_SB2      128
#define WS_STAT_C1  256
#define WS_COEF_C1  384
#define WS_STAT_QKV 512
#define WS_COEF_QKV 768
#define WS_STAT_SIM 1024
#define WS_COEF_SIM 1056
#define WS_STAT_OUT 1088
#define WS_COEF_OUT 1344
#define WS_STAT_C2  1600
#define WS_COEF_C2  1728
#define WS_STAT_END 1856

// ---- buffer regions (float offsets) ----
#define WS_R1  4096
#define WS_R2  (WS_R1 + 8388608)
#define WS_R3  (WS_R2 + 8388608)

// ---- pass-kernel LDS byte offsets (80 KiB -> 2 blocks/CU) ----
#define L_QEA 0        // [128 b][128 a] fp16 swz ^((b&7)<<4); later P[i][j]
#define L_KEB 32768    // k_emb same layout; later Pd half [128 i][128 col]
#define L_RET 65536    // build: re [256 d][16 c] swz ^((d&4)<<2); later ve [16 c][256 d] swz ^((c&7)<<4)
#define L_AQ  73728    // q [128 a][16 c]; later V [16 c][128 j] swz ^((c&7)<<4)
#define L_AK  77824    // k rows 8-15; passA: f32 red[] scratch
#define L_V   73728

__device__ __forceinline__ float wred(float v) {
    #pragma unroll
    for (int off = 32; off > 0; off >>= 1) v += __shfl_down(v, off, 64);
    return v;
}

__global__ void k_prep0(const float* __restrict__ lin1, const float* __restrict__ lin2,
                        const float* __restrict__ latent, float* __restrict__ ws) {
    int t = threadIdx.x;
    for (int i = 256 + t; i < WS_STAT_END; i += 256) ws[i] = 0.f;
    const float* lin = (t < 128) ? lin1 : lin2;
    int row = t & 127;
    float s = 0.f;
    for (int l = 0; l < 256; ++l) s += lin[row * 256 + l] * latent[l];
    ws[(t < 128 ? WS_SB1 : WS_SB2) + row] = s;
}

__global__ __launch_bounds__(256) void k_conv1(const float* __restrict__ in,
                                               const float* __restrict__ w,
                                               float* __restrict__ out) {
    __shared__ float ws_[4096];
    int t = threadIdx.x;
    for (int i = t; i < 4096; i += 256) ws_[i] = w[i];
    __syncthreads();
    int p  = blockIdx.x * 256 + t;
    int b  = p >> 14, hw = p & 16383;
    const float* ip = in + b * 64 * 16384 + hw;
    float x[64];
    #pragma unroll
    for (int c = 0; c < 64; ++c) x[c] = ip[c * 16384];
    float* op = out + b * 64 * 16384 + hw;
    for (int o = 0; o < 64; ++o) {
        float acc = 0.f;
        #pragma unroll
        for (int c = 0; c < 64; ++c) acc += ws_[o * 64 + c] * x[c];
        op[o * 16384] = acc;
    }
}

__global__ void k_stats(const float* __restrict__ src, int C, int logK, int MK, int split,
                        float* __restrict__ stat) {
    int c = blockIdx.x % C;
    int chunk = blockIdx.x / C;
    int per = MK / split;
    int base = chunk * per;
    int Km1 = (1 << logK) - 1;
    float s = 0.f, ss = 0.f;
    for (int i = base + threadIdx.x; i < base + per; i += blockDim.x) {
        int m = i >> logK, k = i & Km1;
        float v = src[((m * C + c) << logK) + k];
        s += v; ss += v * v;
    }
    s = wred(s); ss = wred(ss);
    if ((threadIdx.x & 63) == 0) { atomicAdd(&stat[c], s); atomicAdd(&stat[C + c], ss); }
}

__global__ void k_prep_conv1(const float* __restrict__ g, const float* __restrict__ bta,
                             float* __restrict__ ws) {
    int c = threadIdx.x; if (c >= 64) return;
    float cnt = 65536.f;
    float mean = ws[WS_STAT_C1 + c] / cnt;
    float var  = ws[WS_STAT_C1 + 64 + c] / cnt - mean * mean;
    float tt = rsqrtf(var + EPS);
    float ab = g[c] * tt;
    float sc = ws[WS_SB1 + c], bi = ws[WS_SB1 + 64 + c];
    ws[WS_COEF_C1 + c] = sc * ab;
    ws[WS_COEF_C1 + 64 + c] = sc * (bta[c] - mean * ab) + bi;
}

__global__ __launch_bounds__(256) void k_t1t(const float* __restrict__ src, float* __restrict__ dst,
                                             const float* __restrict__ ws,
                                             const float* __restrict__ prelu1) {
    __shared__ float tile[32][33];
    int bid = blockIdx.x;
    int wt = bid & 3, ht = (bid >> 2) & 3, c = (bid >> 4) & 63, b = bid >> 10;
    float A = ws[WS_COEF_C1 + c], Bb = ws[WS_COEF_C1 + 64 + c];
    float slope = *prelu1;
    int tx = threadIdx.x & 31, ty = threadIdx.x >> 5;
    const float* sp = src + ((b * 64 + c) * 128 + ht * 32) * 128 + wt * 32;
    for (int r = 0; r < 4; ++r) {
        float v = sp[(ty + r * 8) * 128 + tx];
        v = A * v + Bb;
        v = v >= 0.f ? v : slope * v;
        tile[ty + r * 8][tx] = v;
    }
    __syncthreads();
    float* dp = dst + b * 1048576 + (wt * 32) * 8192 + c * 128 + ht * 32;
    for (int r = 0; r < 4; ++r)
        dp[(ty + r * 8) * 8192 + tx] = tile[tx][ty + r * 8];
}

__global__ __launch_bounds__(256) void k_qkv(const float* __restrict__ x, const float* __restrict__ w,
                                             float* __restrict__ out, int SB, int SR, int SC) {
    __shared__ float ws_[8192];
    __shared__ float xs[64][128];
    int t = threadIdx.x;
    for (int i = t; i < 8192; i += 256) ws_[i] = w[i];
    int n = blockIdx.x;
    int b = n >> 7, r = n & 127;
    const float* xp = x + b * SB + r * SR;
    for (int i = t; i < 8192; i += 256) {
        int c = i >> 7, a = i & 127;
        xs[c][a] = xp[c * SC + a];
    }
    __syncthreads();
    int a = t & 127, oh = t >> 7;
    float xc[64];
    #pragma unroll
    for (int c = 0; c < 64; ++c) xc[c] = xs[c][a];
    float* op = out + n * 16384 + oh * 8192 + a;
    for (int o = 0; o < 64; ++o) {
        const float* wr = &ws_[(oh * 64 + o) * 64];
        float acc = 0.f;
        #pragma unroll
        for (int c = 0; c < 64; ++c) acc += wr[c] * xc[c];
        op[o * 128] = acc;
    }
}

__global__ void k_prep_qkv(const float* __restrict__ g, const float* __restrict__ bta,
                           float* __restrict__ ws) {
    int c = threadIdx.x; if (c >= 128) return;
    float cnt = 65536.f;
    float mean = ws[WS_STAT_QKV + c] / cnt;
    float var  = ws[WS_STAT_QKV + 128 + c] / cnt - mean * mean;
    float tt = rsqrtf(var + EPS);
    float A = g[c] * tt;
    ws[WS_COEF_QKV + c] = A;
    ws[WS_COEF_QKV + 128 + c] = bta[c] - mean * A;
}

// ---- shared device helpers for passes (512-thread versions) ----
__device__ __forceinline__ void stage_aqk(unsigned char* L, const float* qkv, const float* ws,
                                          int n, int g, int t) {
    const float* qp = qkv + n * 16384 + g * 32 * 128;
    #pragma unroll
    for (int k = 0; k < 4; ++k) {
        int i = t + k * 512;
        int a = i & 127, cc = i >> 7;
        float v = ws[WS_COEF_QKV + g * 32 + cc] * qp[cc * 128 + a] + ws[WS_COEF_QKV + 128 + g * 32 + cc];
        _Float16 h = (_Float16)v;
        int off = a * 32 + ((cc * 2) ^ ((a & 4) << 2));
        *(_Float16*)(L + L_AQ + off) = (cc < 8) ? h : (_Float16)0.f;
        *(_Float16*)(L + L_AK + off) = (cc < 8) ? (_Float16)0.f : h;
    }
}

__device__ __forceinline__ void stage_ret(unsigned char* L, const float* remb, int crow0, int t) {
    #pragma unroll
    for (int k = 0; k < 8; ++k) {
        int i = t + k * 512;
        int d = i & 255, c = i >> 8;
        float v = (d < 255) ? remb[(crow0 + c) * 255 + d] : 0.f;
        *(_Float16*)(L + L_RET + d * 32 + ((c * 2) ^ ((d & 4) << 2))) = (_Float16)v;
    }
}

// build q_emb/k_emb via diag-MFMA, band-trimmed; one a-tile per wave (8 waves)
template <bool STATS>
__device__ __forceinline__ void build_emb(unsigned char* L, int w, int l15, int g4, float* s) {
    int at = w;
    int arow = at * 16 + l15;
    int aoff = arow * 32 + ((g4 * 8) ^ ((arow & 4) << 2));
    h4 aq = *(const h4*)(L + L_AQ + aoff);
    h4 ak = *(const h4*)(L + L_AK + aoff);
    int abase = at * 16 + g4 * 4;
    for (int m = 0; m < 9; ++m) {
        int drow = (at + m) * 16 + l15;
        h4 bf = *(const h4*)(L + L_RET + drow * 32 + ((g4 * 8) ^ ((drow & 4) << 2)));
        f4 z = {0.f, 0.f, 0.f, 0.f};
        f4 dq = __builtin_amdgcn_mfma_f32_16x16x16f16(aq, bf, z, 0, 0, 0);
        f4 dk = __builtin_amdgcn_mfma_f32_16x16x16f16(ak, bf, z, 0, 0, 0);
        #pragma unroll
        for (int r = 0; r < 4; ++r) {
            int a = abase + r;
            int b = 127 + a - drow;
            if (b >= 0 && b < 128) {
                int off = b * 256 + ((a * 2) ^ ((b & 7) << 4));
                *(_Float16*)(L + L_QEA + off) = (_Float16)dq[r];
                *(_Float16*)(L + L_KEB + off) = (_Float16)dk[r];
                if (STATS) {
                    s[0] += dq[r]; s[1] += dq[r] * dq[r];
                    s[2] += dk[r]; s[3] += dk[r] * dk[r];
                }
            }
        }
    }
}

// one i-tile (i0) x 8 j-tiles of qk
__device__ __forceinline__ void qk_mfma(unsigned char* L, int i0, int l15, int g4, f4 acc[8]) {
    h8 af[4];
    #pragma unroll
    for (int ks = 0; ks < 4; ++ks) {
        int row = i0 + l15;
        af[ks] = *(const h8*)(L + L_QEA + row * 256 + ((ks * 64 + g4 * 16) ^ ((row & 7) << 4)));
    }
    #pragma unroll
    for (int tj = 0; tj < 8; ++tj) {
        h8 bf[4];
        #pragma unroll
        for (int ks = 0; ks < 4; ++ks) {
            int row = tj * 16 + l15;
            bf[ks] = *(const h8*)(L + L_KEB + row * 256 + ((ks * 64 + g4 * 16) ^ ((row & 7) << 4)));
        }
        f4 c = {0.f, 0.f, 0.f, 0.f};
        #pragma unroll
        for (int ks = 0; ks < 4; ++ks)
            c = __builtin_amdgcn_mfma_f32_16x16x32_f16(af[ks], bf[ks], c, 0, 0, 0);
        acc[tj] = c;
    }
}

// passA: build emb + qk, accumulate sim stats only. 512 threads, 8 waves.
__global__ __launch_bounds__(512, 4) void k_passA(const float* __restrict__ qkv,
                                                  const float* __restrict__ remb,
                                                  float* __restrict__ ws) {
    __shared__ __align__(16) unsigned char L[81920];
    int t = threadIdx.x;
    int lane = t & 63, w = t >> 6;
    int l15 = lane & 15, g4 = lane >> 4;
    int n = blockIdx.x >> 2, g = blockIdx.x & 3;

    stage_aqk(L, qkv, ws, n, g, t);
    stage_ret(L, remb, 0, t);
    __syncthreads();

    float es[4] = {0.f, 0.f, 0.f, 0.f};
    build_emb<true>(L, w, l15, g4, es);
    __syncthreads();

    float* red = (float*)(L + L_AK);   // A_k region dead now
    #pragma unroll
    for (int k = 0; k < 4; ++k) es[k] = wred(es[k]);
    if (lane == 0) {
        red[w * 4 + 0] = es[0]; red[w * 4 + 1] = es[1];
        red[w * 4 + 2] = es[2]; red[w * 4 + 3] = es[3];
    }

    f4 acc[8];
    qk_mfma(L, w * 16, l15, g4, acc);

    float s = 0.f, ss = 0.f;
    #pragma unroll
    for (int tj = 0; tj < 8; ++tj)
        #pragma unroll
        for (int r = 0; r < 4; ++r) { float x = acc[tj][r]; s += x; ss += x * x; }
    s = wred(s); ss = wred(ss);
    if (lane == 0) { red[32 + w * 2] = s; red[33 + w * 2] = ss; }
    __syncthreads();

    if (t < 6) {
        float v = 0.f;
        int dst;
        if (t == 0)      { for (int k = 0; k < 8; ++k) v += red[32 + 2 * k]; dst = WS_STAT_SIM + g; }
        else if (t == 1) { for (int k = 0; k < 8; ++k) v += red[33 + 2 * k]; dst = WS_STAT_SIM + 12 + g; }
        else if (t == 2) { for (int k = 0; k < 8; ++k) v += red[k * 4 + 0];  dst = WS_STAT_SIM + 4 + g; }
        else if (t == 3) { for (int k = 0; k < 8; ++k) v += red[k * 4 + 1];  dst = WS_STAT_SIM + 16 + g; }
        else if (t == 4) { for (int k = 0; k < 8; ++k) v += red[k * 4 + 2];  dst = WS_STAT_SIM + 8 + g; }
        else             { for (int k = 0; k < 8; ++k) v += red[k * 4 + 3];  dst = WS_STAT_SIM + 20 + g; }
        atomicAdd(&ws[dst], v);
    }
}

// passB: rebuild, combine+softmax, am + ame via MFMA. 512 threads, 8 waves.
__global__ __launch_bounds__(512, 4) void k_passB(const float* __restrict__ qkv,
                                                  const float* __restrict__ remb,
                                                  const float* __restrict__ ws,
                                                  float* __restrict__ att) {
    __shared__ __align__(16) unsigned char L[81920];
    int t = threadIdx.x;
    int lane = t & 63, w = t >> 6;
    int l15 = lane & 15, g4 = lane >> 4;
    int n = blockIdx.x >> 2, g = blockIdx.x & 3;

    stage_aqk(L, qkv, ws, n, g, t);
    stage_ret(L, remb, 0, t);
    __syncthreads();

    build_emb<false>(L, w, l15, g4, nullptr);
    __syncthreads();

    // stage V [16 c][128 j] into L_V; ve [16 c][256 d] into L_RET (both regions dead)
    #pragma unroll
    for (int k = 0; k < 4; ++k) {
        int i = t + k * 512;
        int j = i & 127, c = i >> 7;
        int o = g * 32 + 16 + c;
        float v = ws[WS_COEF_QKV + o] * qkv[n * 16384 + o * 128 + j] + ws[WS_COEF_QKV + 128 + o];
        *(_Float16*)(L + L_V + c * 256 + ((j * 2) ^ ((c & 7) << 4))) = (_Float16)v;
    }
    #pragma unroll
    for (int k = 0; k < 8; ++k) {
        int i = t + k * 512;
        int d = i & 255, c = i >> 8;
        float v = (d < 255) ? remb[(16 + c) * 255 + d] : 0.f;
        *(_Float16*)(L + L_RET + c * 512 + ((d * 2) ^ ((c & 7) << 4))) = (_Float16)v;
    }

    int i0 = w * 16;
    f4 acc[8];
    qk_mfma(L, i0, l15, g4, acc);

    float Aqk = ws[WS_COEF_SIM + g], Aqe = ws[WS_COEF_SIM + 4 + g];
    float Ake = ws[WS_COEF_SIM + 8 + g], Cst = ws[WS_COEF_SIM + 12 + g];
    int ib = (i0 + g4 * 4) * 2;
    #pragma unroll
    for (int tj = 0; tj < 8; ++tj) {
        int j = tj * 16 + l15;
        h4 q4 = *(const h4*)(L + L_QEA + j * 256 + (ib ^ ((j & 7) << 4)));
        h4 k4 = *(const h4*)(L + L_KEB + j * 256 + (ib ^ ((j & 7) << 4)));
        #pragma unroll
        for (int r = 0; r < 4; ++r)
            acc[tj][r] = Aqk * acc[tj][r] + Aqe * (float)q4[r] + Ake * (float)k4[r] + Cst;
    }

    // softmax over j, in-register (rows i0+g4*4+r)
    float inv4[4];
    #pragma unroll
    for (int r = 0; r < 4; ++r) {
        float m = acc[0][r];
        #pragma unroll
        for (int tj = 1; tj < 8; ++tj) m = fmaxf(m, acc[tj][r]);
        #pragma unroll
        for (int msk = 1; msk < 16; msk <<= 1) m = fmaxf(m, __shfl_xor(m, msk, 64));
        float s = 0.f;
        #pragma unroll
        for (int tj = 0; tj < 8; ++tj) {
            float e = __expf(acc[tj][r] - m);
            acc[tj][r] = e; s += e;
        }
        #pragma unroll
        for (int msk = 1; msk < 16; msk <<= 1) s += __shfl_xor(s, msk, 64);
        inv4[r] = 1.f / s;
    }
    __syncthreads();   // all reads of qeA/keB (combine) done

    // write P[i][j] -> QEA ; Pd-low half -> KEB (full coverage incl. zeros)
    #pragma unroll
    for (int r = 0; r < 4; ++r) {
        int i = i0 + g4 * 4 + r;
        int swz = (i & 7) << 4;
        float inv = inv4[r];
        #pragma unroll
        for (int tj = 0; tj < 8; ++tj) {
            int j = tj * 16 + l15;
            _Float16 h = (_Float16)(acc[tj][r] * inv);
            *(_Float16*)(L + L_QEA + i * 256 + ((j * 2) ^ swz)) = h;
            int cl = (j >= i) ? (127 + i - j) : j;
            *(_Float16*)(L + L_KEB + i * 256 + ((cl * 2) ^ swz)) = (j >= i) ? h : (_Float16)0.f;
        }
    }
    __syncthreads();

    // am (from P) + ame phase 1 (from Pd-low), one i-tile per wave
    h8 vf[4], vef[4];
    #pragma unroll
    for (int ks = 0; ks < 4; ++ks) {
        vf[ks]  = *(const h8*)(L + L_V   + l15 * 256 + ((ks * 64 + g4 * 16) ^ ((l15 & 7) << 4)));
        vef[ks] = *(const h8*)(L + L_RET + l15 * 512 + ((ks * 64 + g4 * 16) ^ ((l15 & 7) << 4)));
    }
    int row = i0 + l15;
    int sw = (row & 7) << 4;
    f4 cam = {0.f, 0.f, 0.f, 0.f}, cae = {0.f, 0.f, 0.f, 0.f};
    #pragma unroll
    for (int ks = 0; ks < 4; ++ks) {
        h8 pf  = *(const h8*)(L + L_QEA + row * 256 + ((ks * 64 + g4 * 16) ^ sw));
        h8 plf = *(const h8*)(L + L_KEB + row * 256 + ((ks * 64 + g4 * 16) ^ sw));
        cam = __builtin_amdgcn_mfma_f32_16x16x32_f16(vf[ks],  pf,  cam, 0, 0, 0);
        cae = __builtin_amdgcn_mfma_f32_16x16x32_f16(vef[ks], plf, cae, 0, 0, 0);
    }
    __syncthreads();

    // write Pd-high half -> KEB (full coverage incl. zeros)
    #pragma unroll
    for (int r = 0; r < 4; ++r) {
        int i = i0 + g4 * 4 + r;
        int swz = (i & 7) << 4;
        float inv = inv4[r];
        #pragma unroll
        for (int tj = 0; tj < 8; ++tj) {
            int j = tj * 16 + l15;
            _Float16 h = (_Float16)(acc[tj][r] * inv);
            int cl = (j < i) ? (i - 1 - j) : j;
            *(_Float16*)(L + L_KEB + i * 256 + ((cl * 2) ^ swz)) = (j < i) ? h : (_Float16)0.f;
        }
    }
    __syncthreads();

    // ame phase 2 (ve cols 128..255)
    h8 vef2[4];
    #pragma unroll
    for (int ks = 0; ks < 4; ++ks)
        vef2[ks] = *(const h8*)(L + L_RET + l15 * 512 + ((256 + ks * 64 + g4 * 16) ^ ((l15 & 7) << 4)));
    #pragma unroll
    for (int ks = 0; ks < 4; ++ks) {
        h8 phf = *(const h8*)(L + L_KEB + row * 256 + ((ks * 64 + g4 * 16) ^ sw));
        cae = __builtin_amdgcn_mfma_f32_16x16x32_f16(vef2[ks], phf, cae, 0, 0, 0);
    }

    float* ab = att + n * 16384 + (g * 32) * 128;
    int i = i0 + l15;
    #pragma unroll
    for (int r = 0; r < 4; ++r) {
        int c = g4 * 4 + r;
        ab[(2 * c) * 128 + i]     = cam[r];
        ab[(2 * c + 1) * 128 + i] = cae[r];
    }
}

__global__ void k_prep_sim(const float* __restrict__ g, const float* __restrict__ bta,
                           float* __restrict__ ws) {
    int i = threadIdx.x; if (i >= 4) return;
    float cnt = 8388608.f;
    float aa[3], bb[3];
    for (int k = 0; k < 3; ++k) {
        int ch = k * 4 + i;
        float mean = ws[WS_STAT_SIM + ch] / cnt;
        float var  = ws[WS_STAT_SIM + 12 + ch] / cnt - mean * mean;
        float tt = rsqrtf(var + EPS);
        float A = g[ch] * tt;
        aa[k] = A; bb[k] = bta[ch] - mean * A;
    }
    ws[WS_COEF_SIM + i]      = aa[0];
    ws[WS_COEF_SIM + 4 + i]  = aa[1];
    ws[WS_COEF_SIM + 8 + i]  = aa[2];
    ws[WS_COEF_SIM + 12 + i] = bb[0] + bb[1] + bb[2];
}

__global__ void k_prep_out(const float* __restrict__ g, const float* __restrict__ bta,
                           float* __restrict__ ws) {
    int c = threadIdx.x; if (c >= 128) return;
    float cnt = 65536.f;
    float mean = ws[WS_STAT_OUT + c] / cnt;
    float var  = ws[WS_STAT_OUT + 128 + c] / cnt - mean * mean;
    float tt = rsqrtf(var + EPS);
    float A = g[c] * tt;
    ws[WS_COEF_OUT + c] = A;
    ws[WS_COEF_OUT + 128 + c] = bta[c] - mean * A;
}

__global__ __launch_bounds__(256) void k_finish0(const float* __restrict__ att,
                                                 const float* __restrict__ ws,
                                                 float* __restrict__ t2) {
    __shared__ float tile[16][32][33];
    int bid = blockIdx.x;
    int wt = bid & 3, ht = (bid >> 2) & 3, cg = (bid >> 4) & 7, b = bid >> 7;
    int t = threadIdx.x;
    for (int i = t; i < 16384; i += 256) {
        int h = i & 31, w = (i >> 5) & 31, cl = i >> 10;
        int c_out = cg * 8 + (cl >> 1), s = cl & 1;
        int chg = (c_out >> 4) * 32 + (c_out & 15) * 2 + s;
        float v = att[((b * 128 + wt * 32 + w) * 128 + chg) * 128 + ht * 32 + h];
        tile[cl][w][h] = ws[WS_COEF_OUT + chg] * v + ws[WS_COEF_OUT + 128 + chg];
    }
    __syncthreads();
    for (int i = t; i < 8192; i += 256) {
        int w = i & 31, h = (i >> 5) & 31, cl = i >> 10;
        float v = tile[2 * cl][w][h] + tile[2 * cl + 1][w][h];
        t2[((b * 64 + cg * 8 + cl) * 128 + ht * 32 + h) * 128 + wt * 32 + w] = v;
    }
}

__global__ void k_zero2(float* __restrict__ ws) {
    int t = threadIdx.x;
    if (t < 256) ws[WS_STAT_QKV + t] = 0.f;
    if (t < 24)  ws[WS_STAT_SIM + t] = 0.f;
    if (t < 256) ws[WS_STAT_OUT + t] = 0.f;
}

__global__ __launch_bounds__(256) void k_finish1(const float* __restrict__ att,
                                                 const float* __restrict__ ws,
                                                 float* __restrict__ t3) {
    int idx = blockIdx.x * 256 + threadIdx.x;
    int w = idx & 127, h = (idx >> 7) & 127, c = (idx >> 14) & 63, b = idx >> 20;
    int chg = (c >> 4) * 32 + (c & 15) * 2;
    int base = ((b * 128 + h) * 128 + chg) * 128 + w;
    float v0 = att[base], v1 = att[base + 128];
    t3[idx] = ws[WS_COEF_OUT + chg] * v0 + ws[WS_COEF_OUT + 128 + chg]
            + ws[WS_COEF_OUT + chg + 1] * v1 + ws[WS_COEF_OUT + 129 + chg];
}

__global__ __launch_bounds__(256) void k_conv2(const float* __restrict__ t3,
                                               const float* __restrict__ w,
                                               float* __restrict__ out) {
    __shared__ float ws_[4096];
    int t = threadIdx.x;
    for (int i = t; i < 4096; i += 256) ws_[i] = w[i];
    __syncthreads();
    int p = blockIdx.x * 256 + t;
    int b = p >> 12, yx = p & 4095, y = yx >> 6, x = yx & 63;
    const float* tp = t3 + b * 1048576 + (2 * y) * 128 + 2 * x;
    float xc[64];
    #pragma unroll
    for (int c = 0; c < 64; ++c) {
        const float* q = tp + c * 16384;
        xc[c] = 0.25f * (q[0] + q[1] + q[128] + q[129]);
    }
    float* op = out + b * 262144 + yx;
    for (int o = 0; o < 64; ++o) {
        float acc = 0.f;
        #pragma unroll
        for (int c = 0; c < 64; ++c) acc += ws_[o * 64 + c] * xc[c];
        op[o * 4096] = acc;
    }
}

__global__ void k_prep_cbn2(const float* __restrict__ g, const float* __restrict__ bta,
                            float* __restrict__ ws) {
    int c = threadIdx.x; if (c >= 64) return;
    float cnt = 16384.f;
    float mean = ws[WS_STAT_C2 + c] / cnt;
    float var  = ws[WS_STAT_C2 + 64 + c] / cnt - mean * mean;
    float tt = rsqrtf(var + EPS);
    float ab = g[c] * tt;
    float sc = ws[WS_SB2 + c], bi = ws[WS_SB2 + 64 + c];
    ws[WS_COEF_C2 + c] = sc * ab;
    ws[WS_COEF_C2 + 64 + c] = sc * (bta[c] - mean * ab) + bi;
}

__global__ __launch_bounds__(256) void k_final(const float* __restrict__ c2out,
                                               const float* __restrict__ input,
                                               const float* __restrict__ ws,
                                               const float* __restrict__ prelu2,
                                               float* __restrict__ out) {
    int idx = blockIdx.x * 256 + threadIdx.x;
    int x = idx & 63, y = (idx >> 6) & 63, o = (idx >> 12) & 63, b = idx >> 18;
    float v = ws[WS_COEF_C2 + o] * c2out[idx] + ws[WS_COEF_C2 + 64 + o];
    const float* ip = input + ((b * 64 + o) * 128 + 2 * y) * 128 + 2 * x;
    v += 0.25f * (ip[0] + ip[1] + ip[128] + ip[129]);
    float s = *prelu2;
    out[idx] = v >= 0.f ? v : s * v;
}

extern "C" void kernel_launch(void* const* d_in, const int* in_sizes, int n_in,
                              void* d_out, int out_size, void* d_ws, size_t ws_size,
                              hipStream_t stream) {
    const float* input    = (const float*)d_in[0];
    const float* latent   = (const float*)d_in[1];
    const float* w_in     = (const float*)d_in[2];
    const float* cbn1_g   = (const float*)d_in[3];
    const float* cbn1_b   = (const float*)d_in[4];
    const float* cbn1_lin = (const float*)d_in[5];
    const float* prelu1   = (const float*)d_in[6];
    const float* ax_qkv_w[2] = {(const float*)d_in[7],  (const float*)d_in[15]};
    const float* ax_qkv_g[2] = {(const float*)d_in[8],  (const float*)d_in[16]};
    const float* ax_qkv_b[2] = {(const float*)d_in[9],  (const float*)d_in[17]};
    const float* ax_sim_g[2] = {(const float*)d_in[10], (const float*)d_in[18]};
    const float* ax_sim_b[2] = {(const float*)d_in[11], (const float*)d_in[19]};
    const float* ax_rel[2]   = {(const float*)d_in[12], (const float*)d_in[20]};
    const float* ax_out_g[2] = {(const float*)d_in[13], (const float*)d_in[21]};
    const float* ax_out_b[2] = {(const float*)d_in[14], (const float*)d_in[22]};
    const float* w_out    = (const float*)d_in[23];
    const float* cbn2_g   = (const float*)d_in[24];
    const float* cbn2_b   = (const float*)d_in[25];
    const float* cbn2_lin = (const float*)d_in[26];
    const float* prelu2   = (const float*)d_in[27];

    float* ws   = (float*)d_ws;
    float* out0 = ws + WS_R1;
    float* t1t  = ws + WS_R1 + 4194304;
    float* att  = ws + WS_R1;
    float* c2o  = ws + WS_R1;
    float* qkv  = ws + WS_R2;
    float* t23  = ws + WS_R3;
    float* dst  = (float*)d_out;

    k_prep0<<<1, 256, 0, stream>>>(cbn1_lin, cbn2_lin, latent, ws);
    k_conv1<<<256, 256, 0, stream>>>(input, w_in, out0);
    k_stats<<<1024, 256, 0, stream>>>(out0, 64, 14, 65536, 16, ws + WS_STAT_C1);
    k_prep_conv1<<<1, 64, 0, stream>>>(cbn1_g, cbn1_b, ws);
    k_t1t<<<4096, 256, 0, stream>>>(out0, t1t, ws, prelu1);

    // axial 0 (n = b*128 + w, a = h)
    k_qkv<<<512, 256, 0, stream>>>(t1t, ax_qkv_w[0], qkv, 1048576, 8192, 128);
    k_stats<<<1024, 256, 0, stream>>>(qkv, 128, 7, 65536, 8, ws + WS_STAT_QKV);
    k_prep_qkv<<<1, 128, 0, stream>>>(ax_qkv_g[0], ax_qkv_b[0], ws);
    k_passA<<<2048, 512, 0, stream>>>(qkv, ax_rel[0], ws);
    k_prep_sim<<<1, 64, 0, stream>>>(ax_sim_g[0], ax_sim_b[0], ws);
    k_passB<<<2048, 512, 0, stream>>>(qkv, ax_rel[0], ws, att);
    k_stats<<<1024, 256, 0, stream>>>(att, 128, 7, 65536, 8, ws + WS_STAT_OUT);
    k_prep_out<<<1, 128, 0, stream>>>(ax_out_g[0], ax_out_b[0], ws);
    k_finish0<<<512, 256, 0, stream>>>(att, ws, t23);
    k_zero2<<<1, 256, 0, stream>>>(ws);

    // axial 1 (n = b*128 + h, a = w)
    k_qkv<<<512, 256, 0, stream>>>(t23, ax_qkv_w[1], qkv, 1048576, 128, 16384);
    k_stats<<<1024, 256, 0, stream>>>(qkv, 128, 7, 65536, 8, ws + WS_STAT_QKV);
    k_prep_qkv<<<1, 128, 0, stream>>>(ax_qkv_g[1], ax_qkv_b[1], ws);
    k_passA<<<2048, 512, 0, stream>>>(qkv, ax_rel[1], ws);
    k_prep_sim<<<1, 64, 0, stream>>>(ax_sim_g[1], ax_sim_b[1], ws);
    k_passB<<<2048, 512, 0, stream>>>(qkv, ax_rel[1], ws, att);
    k_stats<<<1024, 256, 0, stream>>>(att, 128, 7, 65536, 8, ws + WS_STAT_OUT);
    k_prep_out<<<1, 128, 0, stream>>>(ax_out_g[1], ax_out_b[1], ws);
    k_finish1<<<16384, 256, 0, stream>>>(att, ws, t23);

    k_conv2<<<64, 256, 0, stream>>>(t23, w_out, c2o);
    k_stats<<<256, 256, 0, stream>>>(c2o, 64, 12, 16384, 4, ws + WS_STAT_C2);
    k_prep_cbn2<<<1, 64, 0, stream>>>(cbn2_g, cbn2_b, ws);
    k_final<<<4096, 256, 0, stream>>>(c2o, input, ws, prelu2, dst);
}

// Round 5
// 518.937 us; speedup vs baseline: 3.9850x; 1.0577x over previous
//
#include <hip/hip_runtime.h>

#define EPS 1e-5f

typedef __attribute__((ext_vector_type(4))) _Float16 h4;
typedef __attribute__((ext_vector_type(8))) _Float16 h8;
typedef __attribute__((ext_vector_type(4))) float f4;

// ---- workspace float offsets (stats region; all zeroed by prep0) ----
#define WS_SB1        0
#define WS_SB2        128
#define WS_STAT_C1    256
#define WS_STAT_QKV0  384
#define WS_STAT_QKV1  640
#define WS_STAT_SIM0  896
#define WS_STAT_SIM1  928
#define WS_STAT_OUT0  960
#define WS_STAT_OUT1  1216
#define WS_STAT_C2    1472
#define WS_STAT_END   1600

// ---- buffer regions (float offsets) ----
#define WS_R1  4096
#define WS_R2  (WS_R1 + 8388608)
#define WS_R3  (WS_R2 + 8388608)

// ---- pass-kernel LDS byte offsets (80 KiB -> 2 blocks/CU) ----
#define L_QEA 0        // [128 y][128 x] fp16 swz ^((y&7)<<4); later P[i][j]; later sred
#define L_KEB 32768    // k_emb same; later Pd halves
#define L_RET 65536    // build: re [256 d][16 c] swz ^((d&4)<<2); later ve [16 c][256 d] swz ^((c&7)<<4)
#define L_AQ  73728    // q [128 a][16 c]; later V [16 c][128 j] swz ^((c&7)<<4)
#define L_AK  77824    // k rows 8-15; passA: f32 red[] scratch
#define L_V   73728

__device__ __forceinline__ float wred(float v) {
    #pragma unroll
    for (int off = 32; off > 0; off >>= 1) v += __shfl_down(v, off, 64);
    return v;
}

__global__ void k_prep0(const float* __restrict__ lin1, const float* __restrict__ lin2,
                        const float* __restrict__ latent, float* __restrict__ ws) {
    int t = threadIdx.x;
    for (int i = 256 + t; i < WS_STAT_END; i += 256) ws[i] = 0.f;
    const float* lin = (t < 128) ? lin1 : lin2;
    int row = t & 127;
    float s = 0.f;
    for (int l = 0; l < 256; ++l) s += lin[row * 256 + l] * latent[l];
    ws[(t < 128 ? WS_SB1 : WS_SB2) + row] = s;
}

__global__ __launch_bounds__(256) void k_conv1(const float* __restrict__ in,
                                               const float* __restrict__ w,
                                               float* __restrict__ out) {
    __shared__ float ws_[4096];
    int t = threadIdx.x;
    for (int i = t; i < 4096; i += 256) ws_[i] = w[i];
    __syncthreads();
    int p  = blockIdx.x * 256 + t;
    int b  = p >> 14, hw = p & 16383;
    const float* ip = in + b * 64 * 16384 + hw;
    float x[64];
    #pragma unroll
    for (int c = 0; c < 64; ++c) x[c] = ip[c * 16384];
    float* op = out + b * 64 * 16384 + hw;
    for (int o = 0; o < 64; ++o) {
        float acc = 0.f;
        #pragma unroll
        for (int c = 0; c < 64; ++c) acc += ws_[o * 64 + c] * x[c];
        op[o * 16384] = acc;
    }
}

// f32 per-channel stats over [M][C][K]
__global__ void k_stats(const float* __restrict__ src, int C, int logK, int MK, int split,
                        float* __restrict__ stat) {
    int c = blockIdx.x % C;
    int chunk = blockIdx.x / C;
    int per = MK / split;
    int base = chunk * per;
    int Km1 = (1 << logK) - 1;
    float s = 0.f, ss = 0.f;
    for (int i = base + threadIdx.x; i < base + per; i += blockDim.x) {
        int m = i >> logK, k = i & Km1;
        float v = src[((m * C + c) << logK) + k];
        s += v; ss += v * v;
    }
    s = wred(s); ss = wred(ss);
    if ((threadIdx.x & 63) == 0) { atomicAdd(&stat[c], s); atomicAdd(&stat[C + c], ss); }
}

// fp16 per-channel stats over [M][C][K]
__global__ void k_stats_h(const _Float16* __restrict__ src, int C, int logK, int MK, int split,
                          float* __restrict__ stat) {
    int c = blockIdx.x % C;
    int chunk = blockIdx.x / C;
    int per = MK / split;
    int base = chunk * per;
    int Km1 = (1 << logK) - 1;
    float s = 0.f, ss = 0.f;
    for (int i = base + threadIdx.x; i < base + per; i += blockDim.x) {
        int m = i >> logK, k = i & Km1;
        float v = (float)src[((m * C + c) << logK) + k];
        s += v; ss += v * v;
    }
    s = wred(s); ss = wred(ss);
    if ((threadIdx.x & 63) == 0) { atomicAdd(&stat[c], s); atomicAdd(&stat[C + c], ss); }
}

// out0[b][c][h][w] -> t1t[b][w][c][h], inline cbn1 coef + prelu
__global__ __launch_bounds__(256) void k_t1t(const float* __restrict__ src, float* __restrict__ dst,
                                             const float* __restrict__ ws,
                                             const float* __restrict__ g1,
                                             const float* __restrict__ b1,
                                             const float* __restrict__ prelu1) {
    __shared__ float tile[32][33];
    int bid = blockIdx.x;
    int wt = bid & 3, ht = (bid >> 2) & 3, c = (bid >> 4) & 63, b = bid >> 10;
    float mean = ws[WS_STAT_C1 + c] * (1.f / 65536.f);
    float var  = ws[WS_STAT_C1 + 64 + c] * (1.f / 65536.f) - mean * mean;
    float ab = g1[c] * rsqrtf(var + EPS);
    float sc = ws[WS_SB1 + c], bi = ws[WS_SB1 + 64 + c];
    float A = sc * ab;
    float Bb = sc * (b1[c] - mean * ab) + bi;
    float slope = *prelu1;
    int tx = threadIdx.x & 31, ty = threadIdx.x >> 5;
    const float* sp = src + ((b * 64 + c) * 128 + ht * 32) * 128 + wt * 32;
    for (int r = 0; r < 4; ++r) {
        float v = sp[(ty + r * 8) * 128 + tx];
        v = A * v + Bb;
        v = v >= 0.f ? v : slope * v;
        tile[ty + r * 8][tx] = v;
    }
    __syncthreads();
    float* dp = dst + b * 1048576 + (wt * 32) * 8192 + c * 128 + ht * 32;
    for (int r = 0; r < 4; ++r)
        dp[(ty + r * 8) * 8192 + tx] = tile[tx][ty + r * 8];
}

// qkv[n][o][a] = sum_c w[o][c] * x(b,r,c,a); fp16 output
__global__ __launch_bounds__(256) void k_qkv(const float* __restrict__ x, const float* __restrict__ w,
                                             _Float16* __restrict__ out, int SB, int SR, int SC) {
    __shared__ float ws_[8192];
    __shared__ float xs[64][128];
    int t = threadIdx.x;
    for (int i = t; i < 8192; i += 256) ws_[i] = w[i];
    int n = blockIdx.x;
    int b = n >> 7, r = n & 127;
    const float* xp = x + b * SB + r * SR;
    for (int i = t; i < 8192; i += 256) {
        int c = i >> 7, a = i & 127;
        xs[c][a] = xp[c * SC + a];
    }
    __syncthreads();
    int a = t & 127, oh = t >> 7;
    float xc[64];
    #pragma unroll
    for (int c = 0; c < 64; ++c) xc[c] = xs[c][a];
    _Float16* op = out + n * 16384 + oh * 8192 + a;
    for (int o = 0; o < 64; ++o) {
        const float* wr = &ws_[(oh * 64 + o) * 64];
        float acc = 0.f;
        #pragma unroll
        for (int c = 0; c < 64; ++c) acc += wr[c] * xc[c];
        op[o * 128] = (_Float16)acc;
    }
}

// ---- pass helpers (512 threads) ----
__device__ __forceinline__ void stage_aqk(unsigned char* L, const _Float16* qkv,
                                          const float* statq, const float* qg, const float* qb,
                                          int n, int g, int t) {
    const _Float16* qp = qkv + n * 16384 + g * 32 * 128;
    #pragma unroll
    for (int k = 0; k < 4; ++k) {
        int i = t + k * 512;
        int a = i & 127, cc = i >> 7;
        int ch = g * 32 + cc;
        float mean = statq[ch] * (1.f / 65536.f);
        float var  = statq[128 + ch] * (1.f / 65536.f) - mean * mean;
        float A = qg[ch] * rsqrtf(var + EPS);
        float B = qb[ch] - mean * A;
        float v = A * (float)qp[cc * 128 + a] + B;
        _Float16 h = (_Float16)v;
        int off = a * 32 + ((cc * 2) ^ ((a & 4) << 2));
        *(_Float16*)(L + L_AQ + off) = (cc < 8) ? h : (_Float16)0.f;
        *(_Float16*)(L + L_AK + off) = (cc < 8) ? (_Float16)0.f : h;
    }
}

__device__ __forceinline__ void stage_ret(unsigned char* L, const float* remb, int crow0, int t) {
    #pragma unroll
    for (int k = 0; k < 8; ++k) {
        int i = t + k * 512;
        int d = i & 255, c = i >> 8;
        float v = (d < 255) ? remb[(crow0 + c) * 255 + d] : 0.f;
        *(_Float16*)(L + L_RET + d * 32 + ((c * 2) ^ ((d & 4) << 2))) = (_Float16)v;
    }
}

// diag-MFMA emb build, band-trimmed, bounds check only on m=0/m=8
template <bool STATS>
__device__ __forceinline__ void build_emb(unsigned char* L, int w, int l15, int g4, float* s) {
    int at = w;
    int arow = at * 16 + l15;
    int aoff = arow * 32 + ((g4 * 8) ^ ((arow & 4) << 2));
    h4 aq = *(const h4*)(L + L_AQ + aoff);
    h4 ak = *(const h4*)(L + L_AK + aoff);
    int abase = at * 16 + g4 * 4;
    #pragma unroll
    for (int m = 0; m < 9; ++m) {
        int drow = (at + m) * 16 + l15;
        h4 bf = *(const h4*)(L + L_RET + drow * 32 + ((g4 * 8) ^ ((drow & 4) << 2)));
        f4 z = {0.f, 0.f, 0.f, 0.f};
        f4 dq = __builtin_amdgcn_mfma_f32_16x16x16f16(aq, bf, z, 0, 0, 0);
        f4 dk = __builtin_amdgcn_mfma_f32_16x16x16f16(ak, bf, z, 0, 0, 0);
        #pragma unroll
        for (int r = 0; r < 4; ++r) {
            int a = abase + r;
            int b = 127 + a - drow;
            bool ok = (m == 0 || m == 8) ? (b >= 0 && b < 128) : true;
            if (ok) {
                int off = b * 256 + ((a * 2) ^ ((b & 7) << 4));
                *(_Float16*)(L + L_QEA + off) = (_Float16)dq[r];
                *(_Float16*)(L + L_KEB + off) = (_Float16)dk[r];
                if (STATS) {
                    s[0] += dq[r]; s[1] += dq[r] * dq[r];
                    s[2] += dk[r]; s[3] += dk[r] * dk[r];
                }
            }
        }
    }
}

__device__ __forceinline__ void qk_mfma(unsigned char* L, int i0, int l15, int g4, f4 acc[8]) {
    h8 af[4];
    #pragma unroll
    for (int ks = 0; ks < 4; ++ks) {
        int row = i0 + l15;
        af[ks] = *(const h8*)(L + L_QEA + row * 256 + ((ks * 64 + g4 * 16) ^ ((row & 7) << 4)));
    }
    #pragma unroll
    for (int tj = 0; tj < 8; ++tj) {
        h8 bf[4];
        #pragma unroll
        for (int ks = 0; ks < 4; ++ks) {
            int row = tj * 16 + l15;
            bf[ks] = *(const h8*)(L + L_KEB + row * 256 + ((ks * 64 + g4 * 16) ^ ((row & 7) << 4)));
        }
        f4 c = {0.f, 0.f, 0.f, 0.f};
        #pragma unroll
        for (int ks = 0; ks < 4; ++ks)
            c = __builtin_amdgcn_mfma_f32_16x16x32_f16(af[ks], bf[ks], c, 0, 0, 0);
        acc[tj] = c;
    }
}

// passA: build emb + qk, accumulate sim stats
__global__ __launch_bounds__(512, 4) void k_passA(const _Float16* __restrict__ qkv,
                                                  const float* __restrict__ remb,
                                                  const float* __restrict__ statq,
                                                  const float* __restrict__ qg,
                                                  const float* __restrict__ qb,
                                                  float* __restrict__ statsim) {
    __shared__ __align__(16) unsigned char L[81920];
    int t = threadIdx.x;
    int lane = t & 63, w = t >> 6;
    int l15 = lane & 15, g4 = lane >> 4;
    int n = blockIdx.x >> 2, g = blockIdx.x & 3;

    stage_aqk(L, qkv, statq, qg, qb, n, g, t);
    stage_ret(L, remb, 0, t);
    __syncthreads();

    float es[4] = {0.f, 0.f, 0.f, 0.f};
    build_emb<true>(L, w, l15, g4, es);
    __syncthreads();

    float* red = (float*)(L + L_AK);
    #pragma unroll
    for (int k = 0; k < 4; ++k) es[k] = wred(es[k]);
    if (lane == 0) {
        red[w * 4 + 0] = es[0]; red[w * 4 + 1] = es[1];
        red[w * 4 + 2] = es[2]; red[w * 4 + 3] = es[3];
    }

    f4 acc[8];
    qk_mfma(L, w * 16, l15, g4, acc);

    float s = 0.f, ss = 0.f;
    #pragma unroll
    for (int tj = 0; tj < 8; ++tj)
        #pragma unroll
        for (int r = 0; r < 4; ++r) { float x = acc[tj][r]; s += x; ss += x * x; }
    s = wred(s); ss = wred(ss);
    if (lane == 0) { red[32 + w * 2] = s; red[33 + w * 2] = ss; }
    __syncthreads();

    if (t < 6) {
        float v = 0.f;
        int dst;
        if (t == 0)      { for (int k = 0; k < 8; ++k) v += red[32 + 2 * k]; dst = g; }
        else if (t == 1) { for (int k = 0; k < 8; ++k) v += red[33 + 2 * k]; dst = 12 + g; }
        else if (t == 2) { for (int k = 0; k < 8; ++k) v += red[k * 4 + 0];  dst = 4 + g; }
        else if (t == 3) { for (int k = 0; k < 8; ++k) v += red[k * 4 + 1];  dst = 16 + g; }
        else if (t == 4) { for (int k = 0; k < 8; ++k) v += red[k * 4 + 2];  dst = 8 + g; }
        else             { for (int k = 0; k < 8; ++k) v += red[k * 4 + 3];  dst = 20 + g; }
        atomicAdd(&statsim[dst], v);
    }
}

// passB: rebuild, combine+softmax, am+ame MFMA, fused out-stats
__global__ __launch_bounds__(512, 4) void k_passB(const _Float16* __restrict__ qkv,
                                                  const float* __restrict__ remb,
                                                  const float* __restrict__ statq,
                                                  const float* __restrict__ qg,
                                                  const float* __restrict__ qb,
                                                  const float* __restrict__ statsim,
                                                  const float* __restrict__ simg,
                                                  const float* __restrict__ simb,
                                                  float* __restrict__ att,
                                                  float* __restrict__ statout) {
    __shared__ __align__(16) unsigned char L[81920];
    int t = threadIdx.x;
    int lane = t & 63, w = t >> 6;
    int l15 = lane & 15, g4 = lane >> 4;
    int n = blockIdx.x >> 2, g = blockIdx.x & 3;

    stage_aqk(L, qkv, statq, qg, qb, n, g, t);
    stage_ret(L, remb, 0, t);
    __syncthreads();

    build_emb<false>(L, w, l15, g4, nullptr);
    __syncthreads();

    // stage V and ve
    #pragma unroll
    for (int k = 0; k < 4; ++k) {
        int i = t + k * 512;
        int j = i & 127, c = i >> 7;
        int ch = g * 32 + 16 + c;
        float mean = statq[ch] * (1.f / 65536.f);
        float var  = statq[128 + ch] * (1.f / 65536.f) - mean * mean;
        float A = qg[ch] * rsqrtf(var + EPS);
        float B = qb[ch] - mean * A;
        float v = A * (float)qkv[n * 16384 + ch * 128 + j] + B;
        *(_Float16*)(L + L_V + c * 256 + ((j * 2) ^ ((c & 7) << 4))) = (_Float16)v;
    }
    #pragma unroll
    for (int k = 0; k < 8; ++k) {
        int i = t + k * 512;
        int d = i & 255, c = i >> 8;
        float v = (d < 255) ? remb[(16 + c) * 255 + d] : 0.f;
        *(_Float16*)(L + L_RET + c * 512 + ((d * 2) ^ ((c & 7) << 4))) = (_Float16)v;
    }

    int i0 = w * 16;
    f4 acc[8];
    qk_mfma(L, i0, l15, g4, acc);

    // inline sim coefs
    float Aqk, Aqe, Ake, Cst = 0.f;
    {
        float cnt = 1.f / 8388608.f;
        float A3[3];
        #pragma unroll
        for (int k = 0; k < 3; ++k) {
            int ch = k * 4 + g;
            float mean = statsim[ch] * cnt;
            float var  = statsim[12 + ch] * cnt - mean * mean;
            float A = simg[ch] * rsqrtf(var + EPS);
            A3[k] = A;
            Cst += simb[ch] - mean * A;
        }
        Aqk = A3[0]; Aqe = A3[1]; Ake = A3[2];
    }
    int ib = (i0 + g4 * 4) * 2;
    #pragma unroll
    for (int tj = 0; tj < 8; ++tj) {
        int j = tj * 16 + l15;
        h4 q4 = *(const h4*)(L + L_QEA + j * 256 + (ib ^ ((j & 7) << 4)));
        h4 k4 = *(const h4*)(L + L_KEB + j * 256 + (ib ^ ((j & 7) << 4)));
        #pragma unroll
        for (int r = 0; r < 4; ++r)
            acc[tj][r] = Aqk * acc[tj][r] + Aqe * (float)q4[r] + Ake * (float)k4[r] + Cst;
    }

    // softmax over j
    float inv4[4];
    #pragma unroll
    for (int r = 0; r < 4; ++r) {
        float m = acc[0][r];
        #pragma unroll
        for (int tj = 1; tj < 8; ++tj) m = fmaxf(m, acc[tj][r]);
        #pragma unroll
        for (int msk = 1; msk < 16; msk <<= 1) m = fmaxf(m, __shfl_xor(m, msk, 64));
        float s = 0.f;
        #pragma unroll
        for (int tj = 0; tj < 8; ++tj) {
            float e = __expf(acc[tj][r] - m);
            acc[tj][r] = e; s += e;
        }
        #pragma unroll
        for (int msk = 1; msk < 16; msk <<= 1) s += __shfl_xor(s, msk, 64);
        inv4[r] = 1.f / s;
    }
    __syncthreads();

    // P -> QEA ; Pd-low -> KEB
    #pragma unroll
    for (int r = 0; r < 4; ++r) {
        int i = i0 + g4 * 4 + r;
        int swz = (i & 7) << 4;
        float inv = inv4[r];
        #pragma unroll
        for (int tj = 0; tj < 8; ++tj) {
            int j = tj * 16 + l15;
            _Float16 h = (_Float16)(acc[tj][r] * inv);
            *(_Float16*)(L + L_QEA + i * 256 + ((j * 2) ^ swz)) = h;
            int cl = (j >= i) ? (127 + i - j) : j;
            *(_Float16*)(L + L_KEB + i * 256 + ((cl * 2) ^ swz)) = (j >= i) ? h : (_Float16)0.f;
        }
    }
    __syncthreads();

    // am + ame phase 1
    h8 vf[4], vef[4];
    #pragma unroll
    for (int ks = 0; ks < 4; ++ks) {
        vf[ks]  = *(const h8*)(L + L_V   + l15 * 256 + ((ks * 64 + g4 * 16) ^ ((l15 & 7) << 4)));
        vef[ks] = *(const h8*)(L + L_RET + l15 * 512 + ((ks * 64 + g4 * 16) ^ ((l15 & 7) << 4)));
    }
    int row = i0 + l15;
    int sw = (row & 7) << 4;
    f4 cam = {0.f, 0.f, 0.f, 0.f}, cae = {0.f, 0.f, 0.f, 0.f};
    #pragma unroll
    for (int ks = 0; ks < 4; ++ks) {
        h8 pf  = *(const h8*)(L + L_QEA + row * 256 + ((ks * 64 + g4 * 16) ^ sw));
        h8 plf = *(const h8*)(L + L_KEB + row * 256 + ((ks * 64 + g4 * 16) ^ sw));
        cam = __builtin_amdgcn_mfma_f32_16x16x32_f16(vf[ks],  pf,  cam, 0, 0, 0);
        cae = __builtin_amdgcn_mfma_f32_16x16x32_f16(vef[ks], plf, cae, 0, 0, 0);
    }
    __syncthreads();

    // Pd-high -> KEB
    #pragma unroll
    for (int r = 0; r < 4; ++r) {
        int i = i0 + g4 * 4 + r;
        int swz = (i & 7) << 4;
        float inv = inv4[r];
        #pragma unroll
        for (int tj = 0; tj < 8; ++tj) {
            int j = tj * 16 + l15;
            _Float16 h = (_Float16)(acc[tj][r] * inv);
            int cl = (j < i) ? (i - 1 - j) : j;
            *(_Float16*)(L + L_KEB + i * 256 + ((cl * 2) ^ swz)) = (j < i) ? h : (_Float16)0.f;
        }
    }
    __syncthreads();

    // ame phase 2
    h8 vef2[4];
    #pragma unroll
    for (int ks = 0; ks < 4; ++ks)
        vef2[ks] = *(const h8*)(L + L_RET + l15 * 512 + ((256 + ks * 64 + g4 * 16) ^ ((l15 & 7) << 4)));
    #pragma unroll
    for (int ks = 0; ks < 4; ++ks) {
        h8 phf = *(const h8*)(L + L_KEB + row * 256 + ((ks * 64 + g4 * 16) ^ sw));
        cae = __builtin_amdgcn_mfma_f32_16x16x32_f16(vef2[ks], phf, cae, 0, 0, 0);
    }

    float* ab = att + n * 16384 + (g * 32) * 128;
    int i = i0 + l15;
    #pragma unroll
    for (int r = 0; r < 4; ++r) {
        int c = g4 * 4 + r;
        ab[(2 * c) * 128 + i]     = cam[r];
        ab[(2 * c + 1) * 128 + i] = cae[r];
    }

    // fused out-BN stats: reduce over i within 16-lane group, then waves via LDS
    float* sred = (float*)(L + L_QEA);   // 8w*4g4*4r*4 = 512 floats (all LDS reads done)
    #pragma unroll
    for (int r = 0; r < 4; ++r) {
        float sa = cam[r], qa = cam[r] * cam[r];
        float se = cae[r], qe = cae[r] * cae[r];
        #pragma unroll
        for (int msk = 1; msk < 16; msk <<= 1) {
            sa += __shfl_xor(sa, msk, 64); qa += __shfl_xor(qa, msk, 64);
            se += __shfl_xor(se, msk, 64); qe += __shfl_xor(qe, msk, 64);
        }
        if (l15 == 0) {
            int base = w * 64 + g4 * 16 + r * 4;
            sred[base + 0] = sa; sred[base + 1] = qa;
            sred[base + 2] = se; sred[base + 3] = qe;
        }
    }
    __syncthreads();
    if (t < 64) {
        int lc = t & 31, stat = t >> 5;      // lc = 2c+s
        int c = lc >> 1, s = lc & 1;
        int gg4 = c >> 2, r = c & 3;
        float v = 0.f;
        #pragma unroll
        for (int ww = 0; ww < 8; ++ww)
            v += sred[ww * 64 + gg4 * 16 + r * 4 + 2 * s + stat];
        atomicAdd(&statout[stat * 128 + g * 32 + lc], v);
    }
}

// axial0 finish: inline out-coef table; att[n=b*128+w][ch][h] -> t2[b][c][h][w]
__global__ __launch_bounds__(256) void k_finish0(const float* __restrict__ att,
                                                 const float* __restrict__ statout,
                                                 const float* __restrict__ og,
                                                 const float* __restrict__ ob,
                                                 float* __restrict__ t2) {
    __shared__ float tile[16][32][33];
    __shared__ float cf[256];
    int t = threadIdx.x;
    if (t < 128) {
        float mean = statout[t] * (1.f / 65536.f);
        float var  = statout[128 + t] * (1.f / 65536.f) - mean * mean;
        float A = og[t] * rsqrtf(var + EPS);
        cf[t] = A;
        cf[128 + t] = ob[t] - mean * A;
    }
    __syncthreads();
    int bid = blockIdx.x;
    int wt = bid & 3, ht = (bid >> 2) & 3, cg = (bid >> 4) & 7, b = bid >> 7;
    for (int i = t; i < 16384; i += 256) {
        int h = i & 31, w = (i >> 5) & 31, cl = i >> 10;
        int c_out = cg * 8 + (cl >> 1), s = cl & 1;
        int chg = (c_out >> 4) * 32 + (c_out & 15) * 2 + s;
        float v = att[((b * 128 + wt * 32 + w) * 128 + chg) * 128 + ht * 32 + h];
        tile[cl][w][h] = cf[chg] * v + cf[128 + chg];
    }
    __syncthreads();
    for (int i = t; i < 8192; i += 256) {
        int w = i & 31, h = (i >> 5) & 31, cl = i >> 10;
        float v = tile[2 * cl][w][h] + tile[2 * cl + 1][w][h];
        t2[((b * 64 + cg * 8 + cl) * 128 + ht * 32 + h) * 128 + wt * 32 + w] = v;
    }
}

// axial1 finish: inline coef (wave-uniform); att[n=b*128+h][ch][w] -> t3[b][c][h][w]
__global__ __launch_bounds__(256) void k_finish1(const float* __restrict__ att,
                                                 const float* __restrict__ statout,
                                                 const float* __restrict__ og,
                                                 const float* __restrict__ ob,
                                                 float* __restrict__ t3) {
    int idx = blockIdx.x * 256 + threadIdx.x;
    int w = idx & 127, h = (idx >> 7) & 127, c = (idx >> 14) & 63, b = idx >> 20;
    int chg = (c >> 4) * 32 + (c & 15) * 2;
    float m0 = statout[chg] * (1.f / 65536.f);
    float v0_ = statout[128 + chg] * (1.f / 65536.f) - m0 * m0;
    float A0 = og[chg] * rsqrtf(v0_ + EPS);
    float B0 = ob[chg] - m0 * A0;
    float m1 = statout[chg + 1] * (1.f / 65536.f);
    float v1_ = statout[129 + chg] * (1.f / 65536.f) - m1 * m1;
    float A1 = og[chg + 1] * rsqrtf(v1_ + EPS);
    float B1 = ob[chg + 1] - m1 * A1;
    int base = ((b * 128 + h) * 128 + chg) * 128 + w;
    float v0 = att[base], v1 = att[base + 128];
    t3[idx] = A0 * v0 + B0 + A1 * v1 + B1;
}

__global__ __launch_bounds__(256) void k_conv2(const float* __restrict__ t3,
                                               const float* __restrict__ w,
                                               float* __restrict__ out) {
    __shared__ float ws_[4096];
    int t = threadIdx.x;
    for (int i = t; i < 4096; i += 256) ws_[i] = w[i];
    __syncthreads();
    int p = blockIdx.x * 256 + t;
    int b = p >> 12, yx = p & 4095, y = yx >> 6, x = yx & 63;
    const float* tp = t3 + b * 1048576 + (2 * y) * 128 + 2 * x;
    float xc[64];
    #pragma unroll
    for (int c = 0; c < 64; ++c) {
        const float* q = tp + c * 16384;
        xc[c] = 0.25f * (q[0] + q[1] + q[128] + q[129]);
    }
    float* op = out + b * 262144 + yx;
    for (int o = 0; o < 64; ++o) {
        float acc = 0.f;
        #pragma unroll
        for (int c = 0; c < 64; ++c) acc += ws_[o * 64 + c] * xc[c];
        op[o * 4096] = acc;
    }
}

__global__ __launch_bounds__(256) void k_final(const float* __restrict__ c2out,
                                               const float* __restrict__ input,
                                               const float* __restrict__ ws,
                                               const float* __restrict__ g2,
                                               const float* __restrict__ b2,
                                               const float* __restrict__ prelu2,
                                               float* __restrict__ out) {
    int idx = blockIdx.x * 256 + threadIdx.x;
    int x = idx & 63, y = (idx >> 6) & 63, o = (idx >> 12) & 63, b = idx >> 18;
    float mean = ws[WS_STAT_C2 + o] * (1.f / 16384.f);
    float var  = ws[WS_STAT_C2 + 64 + o] * (1.f / 16384.f) - mean * mean;
    float ab = g2[o] * rsqrtf(var + EPS);
    float sc = ws[WS_SB2 + o], bi = ws[WS_SB2 + 64 + o];
    float A = sc * ab;
    float B = sc * (b2[o] - mean * ab) + bi;
    float v = A * c2out[idx] + B;
    const float* ip = input + ((b * 64 + o) * 128 + 2 * y) * 128 + 2 * x;
    v += 0.25f * (ip[0] + ip[1] + ip[128] + ip[129]);
    float s = *prelu2;
    out[idx] = v >= 0.f ? v : s * v;
}

extern "C" void kernel_launch(void* const* d_in, const int* in_sizes, int n_in,
                              void* d_out, int out_size, void* d_ws, size_t ws_size,
                              hipStream_t stream) {
    const float* input    = (const float*)d_in[0];
    const float* latent   = (const float*)d_in[1];
    const float* w_in     = (const float*)d_in[2];
    const float* cbn1_g   = (const float*)d_in[3];
    const float* cbn1_b   = (const float*)d_in[4];
    const float* cbn1_lin = (const float*)d_in[5];
    const float* prelu1   = (const float*)d_in[6];
    const float* ax_qkv_w[2] = {(const float*)d_in[7],  (const float*)d_in[15]};
    const float* ax_qkv_g[2] = {(const float*)d_in[8],  (const float*)d_in[16]};
    const float* ax_qkv_b[2] = {(const float*)d_in[9],  (const float*)d_in[17]};
    const float* ax_sim_g[2] = {(const float*)d_in[10], (const float*)d_in[18]};
    const float* ax_sim_b[2] = {(const float*)d_in[11], (const float*)d_in[19]};
    const float* ax_rel[2]   = {(const float*)d_in[12], (const float*)d_in[20]};
    const float* ax_out_g[2] = {(const float*)d_in[13], (const float*)d_in[21]};
    const float* ax_out_b[2] = {(const float*)d_in[14], (const float*)d_in[22]};
    const float* w_out    = (const float*)d_in[23];
    const float* cbn2_g   = (const float*)d_in[24];
    const float* cbn2_b   = (const float*)d_in[25];
    const float* cbn2_lin = (const float*)d_in[26];
    const float* prelu2   = (const float*)d_in[27];

    float* ws    = (float*)d_ws;
    float* out0  = ws + WS_R1;
    float* t1t   = ws + WS_R1 + 4194304;
    float* att   = ws + WS_R1;
    float* c2o   = ws + WS_R1;
    _Float16* qkvh = (_Float16*)(ws + WS_R2);
    float* t23   = ws + WS_R3;
    float* dst   = (float*)d_out;

    k_prep0<<<1, 256, 0, stream>>>(cbn1_lin, cbn2_lin, latent, ws);
    k_conv1<<<256, 256, 0, stream>>>(input, w_in, out0);
    k_stats<<<1024, 256, 0, stream>>>(out0, 64, 14, 65536, 16, ws + WS_STAT_C1);
    k_t1t<<<4096, 256, 0, stream>>>(out0, t1t, ws, cbn1_g, cbn1_b, prelu1);

    // axial 0 (n = b*128 + w, a = h)
    k_qkv<<<512, 256, 0, stream>>>(t1t, ax_qkv_w[0], qkvh, 1048576, 8192, 128);
    k_stats_h<<<1024, 256, 0, stream>>>(qkvh, 128, 7, 65536, 8, ws + WS_STAT_QKV0);
    k_passA<<<2048, 512, 0, stream>>>(qkvh, ax_rel[0], ws + WS_STAT_QKV0,
                                      ax_qkv_g[0], ax_qkv_b[0], ws + WS_STAT_SIM0);
    k_passB<<<2048, 512, 0, stream>>>(qkvh, ax_rel[0], ws + WS_STAT_QKV0,
                                      ax_qkv_g[0], ax_qkv_b[0], ws + WS_STAT_SIM0,
                                      ax_sim_g[0], ax_sim_b[0], att, ws + WS_STAT_OUT0);
    k_finish0<<<512, 256, 0, stream>>>(att, ws + WS_STAT_OUT0, ax_out_g[0], ax_out_b[0], t23);

    // axial 1 (n = b*128 + h, a = w)
    k_qkv<<<512, 256, 0, stream>>>(t23, ax_qkv_w[1], qkvh, 1048576, 128, 16384);
    k_stats_h<<<1024, 256, 0, stream>>>(qkvh, 128, 7, 65536, 8, ws + WS_STAT_QKV1);
    k_passA<<<2048, 512, 0, stream>>>(qkvh, ax_rel[1], ws + WS_STAT_QKV1,
                                      ax_qkv_g[1], ax_qkv_b[1], ws + WS_STAT_SIM1);
    k_passB<<<2048, 512, 0, stream>>>(qkvh, ax_rel[1], ws + WS_STAT_QKV1,
                                      ax_qkv_g[1], ax_qkv_b[1], ws + WS_STAT_SIM1,
                                      ax_sim_g[1], ax_sim_b[1], att, ws + WS_STAT_OUT1);
    k_finish1<<<16384, 256, 0, stream>>>(att, ws + WS_STAT_OUT1, ax_out_g[1], ax_out_b[1], t23);

    k_conv2<<<64, 256, 0, stream>>>(t23, w_out, c2o);
    k_stats<<<256, 256, 0, stream>>>(c2o, 64, 12, 16384, 4, ws + WS_STAT_C2);
    k_final<<<4096, 256, 0, stream>>>(c2o, input, ws, cbn2_g, cbn2_b, prelu2, dst);
}